// Round 1
// baseline (300555.859 us; speedup 1.0000x reference)
//
#include <hip/hip_runtime.h>
#include <hip/hip_cooperative_groups.h>

namespace cg = cooperative_groups;

#define DIM   512
#define QKVW  1536
#define MLPD  2048
#define NB    256
#define NT    256
#define NLAY  4
#define GRID  256

typedef __attribute__((ext_vector_type(8))) short short8;
typedef __attribute__((ext_vector_type(4))) float floatx4;

static __device__ __forceinline__ float b2f(unsigned short x){
    return __uint_as_float(((unsigned int)x) << 16);
}
static __device__ __forceinline__ unsigned short f2b(float f){
    unsigned int u = __float_as_uint(f);
    u += 0x7fffu + ((u >> 16) & 1u);
    return (unsigned short)(u >> 16);
}

// ---------------- one-time weight transpose+cast: src f32[K][N] -> dst bf16[N][K] ----------------
__global__ __launch_bounds__(256) void k_transpose(const float* __restrict__ src,
        unsigned short* __restrict__ dst, int K, int N){
    __shared__ unsigned short tile[64][65];
    int r0 = blockIdx.x * 64, c0 = blockIdx.y * 64;
    int tx = threadIdx.x & 63, ty = threadIdx.x >> 6;
    #pragma unroll
    for (int i = 0; i < 16; ++i){
        int r = ty + 4 * i;
        tile[r][tx] = f2b(src[(size_t)(r0 + r) * N + c0 + tx]);
    }
    __syncthreads();
    #pragma unroll
    for (int i = 0; i < 16; ++i){
        int r = ty + 4 * i;
        dst[(size_t)(c0 + r) * K + r0 + tx] = tile[tx][r];
    }
}

// ---------------- shared GEMM building blocks ----------------
static __device__ __forceinline__ void stage64(const unsigned short* __restrict__ g,
        int rstride, unsigned short* lds){
    int r = threadIdx.x >> 2, s = threadIdx.x & 3;
    const int4* src = (const int4*)(g + (size_t)r * rstride + s * 16);
    int4* dst = (int4*)(lds + r * 72 + s * 16);
    dst[0] = src[0];
    dst[1] = src[1];
}

static __device__ __forceinline__ void mma_chunk(const unsigned short* __restrict__ A_s, int astride,
        const unsigned short* __restrict__ B_s, floatx4 acc[2][2], int wm, int wn, int lm, int lq){
    #pragma unroll
    for (int ks = 0; ks < 2; ++ks){
        short8 a0 = *(const short8*)(A_s + (wm*32 + lm) * astride + ks*32 + lq*8);
        short8 a1 = *(const short8*)(A_s + (wm*32 + 16 + lm) * astride + ks*32 + lq*8);
        short8 b0 = *(const short8*)(B_s + (wn*32 + lm) * 72 + ks*32 + lq*8);
        short8 b1 = *(const short8*)(B_s + (wn*32 + 16 + lm) * 72 + ks*32 + lq*8);
        acc[0][0] = __builtin_amdgcn_mfma_f32_16x16x32_bf16(a0, b0, acc[0][0], 0, 0, 0);
        acc[0][1] = __builtin_amdgcn_mfma_f32_16x16x32_bf16(a0, b1, acc[0][1], 0, 0, 0);
        acc[1][0] = __builtin_amdgcn_mfma_f32_16x16x32_bf16(a1, b0, acc[1][0], 0, 0, 0);
        acc[1][1] = __builtin_amdgcn_mfma_f32_16x16x32_bf16(a1, b1, acc[1][1], 0, 0, 0);
    }
}

static __device__ __forceinline__ void ln_stats(const float* __restrict__ seq, int row0,
        float* mu_s, float* rs_s, float* red){
    int r = threadIdx.x >> 2, p = threadIdx.x & 3;
    const float* s = seq + (size_t)(row0 + r) * DIM + p * 128;
    float sm = 0.f, ss = 0.f;
    for (int k = 0; k < 128; k += 4){
        float4 v = *(const float4*)(s + k);
        sm += v.x + v.y + v.z + v.w;
        ss += v.x*v.x + v.y*v.y + v.z*v.z + v.w*v.w;
    }
    red[r*8 + p] = sm;
    red[r*8 + 4 + p] = ss;
    __syncthreads();
    if (threadIdx.x < 64){
        int rr = threadIdx.x;
        float s4 = red[rr*8+0] + red[rr*8+1] + red[rr*8+2] + red[rr*8+3];
        float q4 = red[rr*8+4] + red[rr*8+5] + red[rr*8+6] + red[rr*8+7];
        float mu = s4 * (1.f / DIM);
        float var = q4 * (1.f / DIM) - mu * mu;
        mu_s[rr] = mu;
        rs_s[rr] = rsqrtf(var + 1e-6f);
    }
    __syncthreads();
}

static __device__ __forceinline__ void stageA_ln(const float* __restrict__ seq, int row0, int kk,
        const float* __restrict__ lns, const float* __restrict__ lnb,
        const float* mu_s, const float* rs_s, unsigned short* lds){
    int r = threadIdx.x >> 2, s = threadIdx.x & 3;
    const float* src = seq + (size_t)(row0 + r) * DIM + kk + s * 16;
    float mu = mu_s[r], rs = rs_s[r];
    unsigned short tmp[16];
    #pragma unroll
    for (int j = 0; j < 16; ++j){
        float g = lns[kk + s*16 + j];
        float bb = lnb[kk + s*16 + j];
        tmp[j] = f2b((src[j] - mu) * rs * g + bb);
    }
    int4* dst = (int4*)(lds + r * 72 + s * 16);
    dst[0] = *(int4*)(tmp);
    dst[1] = *(int4*)(tmp + 8);
}

// ---------------- persistent cooperative kernel: whole T loop ----------------
struct P {
    const float* obs; const int* dones; const float* mem0;
    const unsigned short* memkT;
    const unsigned short* qkvT; const unsigned short* woT;
    const unsigned short* w1T;  const unsigned short* w2T;
    const float *ln1s, *ln1b, *bq, *bk, *bv, *bo, *ln2s, *ln2b, *b1, *b2;
    float* seq0; float* seq1;
    unsigned short* qkv; unsigned short* h1;
    float* out;
};

__global__ __launch_bounds__(256) void k_persist(P p){
    cg::grid_group grid = cg::this_grid();
    __shared__ __align__(16) char smem[43520];
    unsigned short* A_s  = (unsigned short*)smem;           // 64*72 bf16 = 9216 B
    unsigned short* B_s  = A_s + 64*72;                     // 9216 B
    float* red  = (float*)(B_s + 64*72);                    // 2048 B
    float* mu_s = red + 64*8;                               // 256 B
    float* rs_s = mu_s + 64;                                // 256 B
    unsigned short* O_s  = (unsigned short*)smem;           // attn phase: 64*264 = 33792 B
    unsigned short* B2_s = O_s + 64*264;                    // 9216 B (total 43008)

    const int bid  = blockIdx.x;
    const int wave = threadIdx.x >> 6, lane = threadIdx.x & 63;
    const int wm = wave >> 1, wn = wave & 1, lm = lane & 15, lq = lane >> 4;
    const floatx4 z = {0.f, 0.f, 0.f, 0.f};

    for (int t = 0; t < NT; ++t){
        float* scur  = (t & 1) ? p.seq1 : p.seq0;
        float* sprev = (t & 1) ? p.seq0 : p.seq1;
        const float* obs_t  = p.obs + (size_t)t * NB * DIM;
        const int* dones_t  = p.dones + t * NB;
        float* outprev = p.out + (size_t)(t > 0 ? t - 1 : 0) * NB * DIM;

        // ---- phase M: mem gating + mem_tok GEMM; build seq; emit out[t-1] ----
        if (bid < 32){
            int n0 = (bid & 7) * 64, m0 = (bid >> 3) * 64;
            floatx4 acc[2][2] = {{z, z}, {z, z}};
            for (int kk = 0; kk < DIM; kk += 64){
                __syncthreads();
                {
                    int r = threadIdx.x >> 2, s = threadIdx.x & 3;
                    int b = m0 + r;
                    int done = dones_t[b];
                    unsigned short tmp[16];
                    if (t == 0){
                        const float* src = p.mem0 + (size_t)b * DIM + kk + s * 16;
                        #pragma unroll
                        for (int j = 0; j < 16; ++j) tmp[j] = done ? (unsigned short)0 : f2b(src[j]);
                    } else {
                        const float* src = sprev + (size_t)(2*b + 1) * DIM + kk + s * 16;
                        #pragma unroll
                        for (int j = 0; j < 16; ++j){
                            float x = src[j];
                            if (n0 == 0) outprev[(size_t)b * DIM + kk + s*16 + j] = x;
                            tmp[j] = done ? (unsigned short)0 : f2b(x);
                        }
                    }
                    int4* dst = (int4*)(A_s + r * 72 + s * 16);
                    dst[0] = *(int4*)tmp;
                    dst[1] = *(int4*)(tmp + 8);
                }
                stage64(p.memkT + (size_t)n0 * DIM + kk, DIM, B_s);
                __syncthreads();
                mma_chunk(A_s, 72, B_s, acc, wm, wn, lm, lq);
            }
            #pragma unroll
            for (int fm = 0; fm < 2; ++fm)
            #pragma unroll
            for (int fn = 0; fn < 2; ++fn)
            #pragma unroll
            for (int i = 0; i < 4; ++i){
                int b = m0 + wm*32 + fm*16 + lq*4 + i;
                int c = n0 + wn*32 + fn*16 + lm;
                scur[(size_t)(2*b) * DIM + c] = acc[fm][fn][i];
                scur[(size_t)(2*b + 1) * DIM + c] = obs_t[(size_t)b * DIM + c];
            }
        }
        __builtin_amdgcn_fence(__ATOMIC_RELEASE, "agent");
        grid.sync();
        __builtin_amdgcn_fence(__ATOMIC_ACQUIRE, "agent");

        for (int l = 0; l < NLAY; ++l){
            // ---- phase Q: LN1 + fused QKV GEMM (+bias) ----
            {
                const unsigned short* wT = p.qkvT + (size_t)l * 786432;
                const float* lns = p.ln1s + l * DIM;
                const float* lnb = p.ln1b + l * DIM;
                if (bid < 192){
                    int n0 = (bid % 24) * 64;
                    int m0 = (bid / 24) * 64;
                    ln_stats(scur, m0, mu_s, rs_s, red);
                    floatx4 acc[2][2] = {{z, z}, {z, z}};
                    for (int kk = 0; kk < DIM; kk += 64){
                        __syncthreads();
                        stageA_ln(scur, m0, kk, lns, lnb, mu_s, rs_s, A_s);
                        stage64(wT + (size_t)n0 * DIM + kk, DIM, B_s);
                        __syncthreads();
                        mma_chunk(A_s, 72, B_s, acc, wm, wn, lm, lq);
                    }
                    int sec = n0 >> 9;
                    const float* bias = (sec == 0) ? (p.bq + l*DIM)
                                      : ((sec == 1) ? (p.bk + l*DIM) : (p.bv + l*DIM));
                    int nsec = n0 & 511;
                    #pragma unroll
                    for (int fm = 0; fm < 2; ++fm)
                    #pragma unroll
                    for (int fn = 0; fn < 2; ++fn)
                    #pragma unroll
                    for (int i = 0; i < 4; ++i){
                        int row = m0 + wm*32 + fm*16 + lq*4 + i;
                        int cl = wn*32 + fn*16 + lm;
                        float v = acc[fm][fn][i] + bias[nsec + cl];
                        p.qkv[(size_t)row * QKVW + n0 + cl] = f2b(v);
                    }
                }
            }
            __builtin_amdgcn_fence(__ATOMIC_RELEASE, "agent");
            grid.sync();
            __builtin_amdgcn_fence(__ATOMIC_ACQUIRE, "agent");

            // ---- phase A: 2-token attention + O GEMM, residual atomicAdd ----
            {
                const unsigned short* wT = p.woT + (size_t)l * 262144;
                const float* bo_l = p.bo + l * DIM;
                if (bid < 128){
                    int n0 = (bid & 7) * 64;
                    int m0 = ((bid >> 3) & 7) * 64;
                    int sp = bid >> 6;
                    if (threadIdx.x < 128){
                        int b_l = threadIdx.x >> 2, h_l = threadIdx.x & 3;
                        int h = sp * 4 + h_l;
                        const unsigned short* q0 = p.qkv + (size_t)(m0 + 2*b_l) * QKVW + h * 64;
                        const unsigned short* q1 = q0 + QKVW;
                        const unsigned short* k0p = q0 + 512;
                        const unsigned short* k1p = k0p + QKVW;
                        const unsigned short* v0p = q0 + 1024;
                        const unsigned short* v1p = v0p + QKVW;
                        float s00 = 0, s01 = 0, s10 = 0, s11 = 0;
                        for (int f8 = 0; f8 < 8; ++f8){
                            short8 a0 = *(const short8*)(q0 + f8*8);
                            short8 a1 = *(const short8*)(q1 + f8*8);
                            short8 c0 = *(const short8*)(k0p + f8*8);
                            short8 c1 = *(const short8*)(k1p + f8*8);
                            #pragma unroll
                            for (int j = 0; j < 8; ++j){
                                float qa = b2f((unsigned short)a0[j]);
                                float qb = b2f((unsigned short)a1[j]);
                                float ka = b2f((unsigned short)c0[j]);
                                float kb = b2f((unsigned short)c1[j]);
                                s00 += qa*ka; s01 += qa*kb; s10 += qb*ka; s11 += qb*kb;
                            }
                        }
                        s00 *= 0.125f; s01 *= 0.125f; s10 *= 0.125f; s11 *= 0.125f;
                        float m0v = fmaxf(s00, s01), m1v = fmaxf(s10, s11);
                        float e00 = __expf(s00 - m0v), e01 = __expf(s01 - m0v);
                        float e10 = __expf(s10 - m1v), e11 = __expf(s11 - m1v);
                        float i0 = 1.f / (e00 + e01), i1 = 1.f / (e10 + e11);
                        float p00 = e00*i0, p01 = e01*i0, p10 = e10*i1, p11 = e11*i1;
                        for (int f8 = 0; f8 < 8; ++f8){
                            short8 va = *(const short8*)(v0p + f8*8);
                            short8 vb = *(const short8*)(v1p + f8*8);
                            unsigned short o0[8], o1[8];
                            #pragma unroll
                            for (int j = 0; j < 8; ++j){
                                float x0 = b2f((unsigned short)va[j]);
                                float x1 = b2f((unsigned short)vb[j]);
                                o0[j] = f2b(p00*x0 + p01*x1);
                                o1[j] = f2b(p10*x0 + p11*x1);
                            }
                            *(int4*)(O_s + (2*b_l) * 264 + h_l*64 + f8*8) = *(int4*)o0;
                            *(int4*)(O_s + (2*b_l + 1) * 264 + h_l*64 + f8*8) = *(int4*)o1;
                        }
                    }
                    floatx4 acc[2][2] = {{z, z}, {z, z}};
                    for (int c = 0; c < 4; ++c){
                        int kkg = sp * 256 + c * 64;
                        __syncthreads();
                        stage64(wT + (size_t)n0 * DIM + kkg, DIM, B2_s);
                        __syncthreads();
                        mma_chunk(O_s + c * 64, 264, B2_s, acc, wm, wn, lm, lq);
                    }
                    #pragma unroll
                    for (int fm = 0; fm < 2; ++fm)
                    #pragma unroll
                    for (int fn = 0; fn < 2; ++fn)
                    #pragma unroll
                    for (int i = 0; i < 4; ++i){
                        int row = m0 + wm*32 + fm*16 + lq*4 + i;
                        int cc = n0 + wn*32 + fn*16 + lm;
                        float v = acc[fm][fn][i];
                        if (sp == 0) v += bo_l[cc];
                        atomicAdd(&scur[(size_t)row * DIM + cc], v);
                    }
                }
            }
            __builtin_amdgcn_fence(__ATOMIC_RELEASE, "agent");
            grid.sync();
            __builtin_amdgcn_fence(__ATOMIC_ACQUIRE, "agent");

            // ---- phase 1: LN2 + MLP1 + gelu ----
            {
                const unsigned short* wT = p.w1T + (size_t)l * 1048576;
                const float* b1_l = p.b1 + l * MLPD;
                const float* lns = p.ln2s + l * DIM;
                const float* lnb = p.ln2b + l * DIM;
                int n0 = (bid & 31) * 64;
                int m0 = (bid >> 5) * 64;
                ln_stats(scur, m0, mu_s, rs_s, red);
                floatx4 acc[2][2] = {{z, z}, {z, z}};
                for (int kk = 0; kk < DIM; kk += 64){
                    __syncthreads();
                    stageA_ln(scur, m0, kk, lns, lnb, mu_s, rs_s, A_s);
                    stage64(wT + (size_t)n0 * DIM + kk, DIM, B_s);
                    __syncthreads();
                    mma_chunk(A_s, 72, B_s, acc, wm, wn, lm, lq);
                }
                #pragma unroll
                for (int fm = 0; fm < 2; ++fm)
                #pragma unroll
                for (int fn = 0; fn < 2; ++fn)
                #pragma unroll
                for (int i = 0; i < 4; ++i){
                    int row = m0 + wm*32 + fm*16 + lq*4 + i;
                    int cc = n0 + wn*32 + fn*16 + lm;
                    float v = acc[fm][fn][i] + b1_l[cc];
                    float g = 0.5f * v * (1.f + tanhf(0.7978845608028654f * (v + 0.044715f * v * v * v)));
                    p.h1[(size_t)row * MLPD + cc] = f2b(g);
                }
            }
            __builtin_amdgcn_fence(__ATOMIC_RELEASE, "agent");
            grid.sync();
            __builtin_amdgcn_fence(__ATOMIC_ACQUIRE, "agent");

            // ---- phase 2: MLP2 (K=2048 split 4) + residual atomicAdd ----
            {
                const unsigned short* wT = p.w2T + (size_t)l * 1048576;
                const float* b2_l = p.b2 + l * DIM;
                int n0 = (bid & 7) * 64;
                int m0 = ((bid >> 3) & 7) * 64;
                int sp = bid >> 6;
                floatx4 acc[2][2] = {{z, z}, {z, z}};
                for (int c = 0; c < 8; ++c){
                    int kk = sp * 512 + c * 64;
                    __syncthreads();
                    stage64(p.h1 + (size_t)m0 * MLPD + kk, MLPD, A_s);
                    stage64(wT + (size_t)n0 * MLPD + kk, MLPD, B_s);
                    __syncthreads();
                    mma_chunk(A_s, 72, B_s, acc, wm, wn, lm, lq);
                }
                #pragma unroll
                for (int fm = 0; fm < 2; ++fm)
                #pragma unroll
                for (int fn = 0; fn < 2; ++fn)
                #pragma unroll
                for (int i = 0; i < 4; ++i){
                    int row = m0 + wm*32 + fm*16 + lq*4 + i;
                    int cc = n0 + wn*32 + fn*16 + lm;
                    float v = acc[fm][fn][i];
                    if (sp == 0) v += b2_l[cc];
                    atomicAdd(&scur[(size_t)row * DIM + cc], v);
                }
            }
            __builtin_amdgcn_fence(__ATOMIC_RELEASE, "agent");
            grid.sync();
            __builtin_amdgcn_fence(__ATOMIC_ACQUIRE, "agent");
        }
    }

    // ---- flush out[T-1] ----
    {
        const float* sfin = ((NT - 1) & 1) ? p.seq1 : p.seq0;
        float* o = p.out + (size_t)(NT - 1) * NB * DIM;
        for (int idx = bid * 256 + threadIdx.x; idx < NB * DIM; idx += GRID * 256){
            int b = idx >> 9, c = idx & 511;
            o[idx] = sfin[(size_t)(2*b + 1) * DIM + c];
        }
    }
}

// ---------------- fallback per-phase kernels (used only if cooperative launch fails) ----------------
__global__ __launch_bounds__(256) void k_memgemm(int t,
        const float* __restrict__ obs, const int* __restrict__ dones,
        const float* __restrict__ mem0, const float* __restrict__ seqprev,
        const unsigned short* __restrict__ wT, float* __restrict__ seqcur,
        float* __restrict__ outprev){
    __shared__ unsigned short A_s[64*72];
    __shared__ unsigned short B_s[64*72];
    int n0 = blockIdx.x * 64, m0 = blockIdx.y * 64;
    int wave = threadIdx.x >> 6, lane = threadIdx.x & 63;
    int wm = wave >> 1, wn = wave & 1, lm = lane & 15, lq = lane >> 4;
    floatx4 z = {0.f, 0.f, 0.f, 0.f};
    floatx4 acc[2][2] = {{z, z}, {z, z}};
    for (int kk = 0; kk < DIM; kk += 64){
        __syncthreads();
        {
            int r = threadIdx.x >> 2, s = threadIdx.x & 3;
            int b = m0 + r;
            int done = dones[b];
            unsigned short tmp[16];
            if (t == 0){
                const float* src = mem0 + (size_t)b * DIM + kk + s * 16;
                #pragma unroll
                for (int j = 0; j < 16; ++j) tmp[j] = done ? (unsigned short)0 : f2b(src[j]);
            } else {
                const float* src = seqprev + (size_t)(2*b + 1) * DIM + kk + s * 16;
                #pragma unroll
                for (int j = 0; j < 16; ++j){
                    float x = src[j];
                    if (blockIdx.x == 0) outprev[(size_t)b * DIM + kk + s*16 + j] = x;
                    tmp[j] = done ? (unsigned short)0 : f2b(x);
                }
            }
            int4* dst = (int4*)(A_s + r * 72 + s * 16);
            dst[0] = *(int4*)tmp;
            dst[1] = *(int4*)(tmp + 8);
        }
        stage64(wT + (size_t)n0 * DIM + kk, DIM, B_s);
        __syncthreads();
        mma_chunk(A_s, 72, B_s, acc, wm, wn, lm, lq);
    }
    #pragma unroll
    for (int fm = 0; fm < 2; ++fm)
    #pragma unroll
    for (int fn = 0; fn < 2; ++fn)
    #pragma unroll
    for (int i = 0; i < 4; ++i){
        int b = m0 + wm*32 + fm*16 + lq*4 + i;
        int c = n0 + wn*32 + fn*16 + lm;
        seqcur[(size_t)(2*b) * DIM + c] = acc[fm][fn][i];
        seqcur[(size_t)(2*b + 1) * DIM + c] = obs[(size_t)b * DIM + c];
    }
}

__global__ __launch_bounds__(256) void k_qkv(const float* __restrict__ seq,
        const unsigned short* __restrict__ wT,
        const float* __restrict__ bq, const float* __restrict__ bk,
        const float* __restrict__ bv,
        const float* __restrict__ lns, const float* __restrict__ lnb,
        unsigned short* __restrict__ qkv){
    __shared__ unsigned short A_s[64*72];
    __shared__ unsigned short B_s[64*72];
    __shared__ float red[64*8];
    __shared__ float mu_s[64], rs_s[64];
    int n0 = blockIdx.x * 64, m0 = blockIdx.y * 64;
    ln_stats(seq, m0, mu_s, rs_s, red);
    int wave = threadIdx.x >> 6, lane = threadIdx.x & 63;
    int wm = wave >> 1, wn = wave & 1, lm = lane & 15, lq = lane >> 4;
    floatx4 z = {0.f, 0.f, 0.f, 0.f};
    floatx4 acc[2][2] = {{z, z}, {z, z}};
    for (int kk = 0; kk < DIM; kk += 64){
        __syncthreads();
        stageA_ln(seq, m0, kk, lns, lnb, mu_s, rs_s, A_s);
        stage64(wT + (size_t)n0 * DIM + kk, DIM, B_s);
        __syncthreads();
        mma_chunk(A_s, 72, B_s, acc, wm, wn, lm, lq);
    }
    int sec = n0 >> 9;
    const float* bias = (sec == 0) ? bq : ((sec == 1) ? bk : bv);
    int nsec = n0 & 511;
    #pragma unroll
    for (int fm = 0; fm < 2; ++fm)
    #pragma unroll
    for (int fn = 0; fn < 2; ++fn)
    #pragma unroll
    for (int i = 0; i < 4; ++i){
        int row = m0 + wm*32 + fm*16 + lq*4 + i;
        int cl = wn*32 + fn*16 + lm;
        float v = acc[fm][fn][i] + bias[nsec + cl];
        qkv[(size_t)row * QKVW + n0 + cl] = f2b(v);
    }
}

__global__ __launch_bounds__(256) void k_attno(const unsigned short* __restrict__ qkv,
        const unsigned short* __restrict__ wT,
        const float* __restrict__ bo, float* __restrict__ seq){
    __shared__ unsigned short O_s[64*264];
    __shared__ unsigned short B_s[64*72];
    int n0 = blockIdx.x * 64, m0 = blockIdx.y * 64;
    int sp = blockIdx.z;
    if (threadIdx.x < 128){
        int b_l = threadIdx.x >> 2, h_l = threadIdx.x & 3;
        int h = sp * 4 + h_l;
        const unsigned short* q0 = qkv + (size_t)(m0 + 2*b_l) * QKVW + h * 64;
        const unsigned short* q1 = q0 + QKVW;
        const unsigned short* k0p = q0 + 512;
        const unsigned short* k1p = k0p + QKVW;
        const unsigned short* v0p = q0 + 1024;
        const unsigned short* v1p = v0p + QKVW;
        float s00 = 0, s01 = 0, s10 = 0, s11 = 0;
        for (int f8 = 0; f8 < 8; ++f8){
            short8 a0 = *(const short8*)(q0 + f8*8);
            short8 a1 = *(const short8*)(q1 + f8*8);
            short8 c0 = *(const short8*)(k0p + f8*8);
            short8 c1 = *(const short8*)(k1p + f8*8);
            #pragma unroll
            for (int j = 0; j < 8; ++j){
                float qa = b2f((unsigned short)a0[j]);
                float qb = b2f((unsigned short)a1[j]);
                float ka = b2f((unsigned short)c0[j]);
                float kb = b2f((unsigned short)c1[j]);
                s00 += qa*ka; s01 += qa*kb; s10 += qb*ka; s11 += qb*kb;
            }
        }
        s00 *= 0.125f; s01 *= 0.125f; s10 *= 0.125f; s11 *= 0.125f;
        float m0v = fmaxf(s00, s01), m1v = fmaxf(s10, s11);
        float e00 = __expf(s00 - m0v), e01 = __expf(s01 - m0v);
        float e10 = __expf(s10 - m1v), e11 = __expf(s11 - m1v);
        float i0 = 1.f / (e00 + e01), i1 = 1.f / (e10 + e11);
        float p00 = e00*i0, p01 = e01*i0, p10 = e10*i1, p11 = e11*i1;
        for (int f8 = 0; f8 < 8; ++f8){
            short8 va = *(const short8*)(v0p + f8*8);
            short8 vb = *(const short8*)(v1p + f8*8);
            unsigned short o0[8], o1[8];
            #pragma unroll
            for (int j = 0; j < 8; ++j){
                float x0 = b2f((unsigned short)va[j]);
                float x1 = b2f((unsigned short)vb[j]);
                o0[j] = f2b(p00*x0 + p01*x1);
                o1[j] = f2b(p10*x0 + p11*x1);
            }
            *(int4*)(O_s + (2*b_l) * 264 + h_l*64 + f8*8) = *(int4*)o0;
            *(int4*)(O_s + (2*b_l + 1) * 264 + h_l*64 + f8*8) = *(int4*)o1;
        }
    }
    int wave = threadIdx.x >> 6, lane = threadIdx.x & 63;
    int wm = wave >> 1, wn = wave & 1, lm = lane & 15, lq = lane >> 4;
    floatx4 z = {0.f, 0.f, 0.f, 0.f};
    floatx4 acc[2][2] = {{z, z}, {z, z}};
    for (int c = 0; c < 4; ++c){
        int kkg = sp * 256 + c * 64;
        __syncthreads();
        stage64(wT + (size_t)n0 * DIM + kkg, DIM, B_s);
        __syncthreads();
        mma_chunk(O_s + c * 64, 264, B_s, acc, wm, wn, lm, lq);
    }
    #pragma unroll
    for (int fm = 0; fm < 2; ++fm)
    #pragma unroll
    for (int fn = 0; fn < 2; ++fn)
    #pragma unroll
    for (int i = 0; i < 4; ++i){
        int row = m0 + wm*32 + fm*16 + lq*4 + i;
        int cc = n0 + wn*32 + fn*16 + lm;
        float v = acc[fm][fn][i];
        if (sp == 0) v += bo[cc];
        atomicAdd(&seq[(size_t)row * DIM + cc], v);
    }
}

__global__ __launch_bounds__(256) void k_mlp1(const float* __restrict__ seq,
        const unsigned short* __restrict__ wT, const float* __restrict__ b1,
        const float* __restrict__ lns, const float* __restrict__ lnb,
        unsigned short* __restrict__ h1){
    __shared__ unsigned short A_s[64*72];
    __shared__ unsigned short B_s[64*72];
    __shared__ float red[64*8];
    __shared__ float mu_s[64], rs_s[64];
    int n0 = blockIdx.x * 64, m0 = blockIdx.y * 64;
    ln_stats(seq, m0, mu_s, rs_s, red);
    int wave = threadIdx.x >> 6, lane = threadIdx.x & 63;
    int wm = wave >> 1, wn = wave & 1, lm = lane & 15, lq = lane >> 4;
    floatx4 z = {0.f, 0.f, 0.f, 0.f};
    floatx4 acc[2][2] = {{z, z}, {z, z}};
    for (int kk = 0; kk < DIM; kk += 64){
        __syncthreads();
        stageA_ln(seq, m0, kk, lns, lnb, mu_s, rs_s, A_s);
        stage64(wT + (size_t)n0 * DIM + kk, DIM, B_s);
        __syncthreads();
        mma_chunk(A_s, 72, B_s, acc, wm, wn, lm, lq);
    }
    #pragma unroll
    for (int fm = 0; fm < 2; ++fm)
    #pragma unroll
    for (int fn = 0; fn < 2; ++fn)
    #pragma unroll
    for (int i = 0; i < 4; ++i){
        int row = m0 + wm*32 + fm*16 + lq*4 + i;
        int cc = n0 + wn*32 + fn*16 + lm;
        float v = acc[fm][fn][i] + b1[cc];
        float g = 0.5f * v * (1.f + tanhf(0.7978845608028654f * (v + 0.044715f * v * v * v)));
        h1[(size_t)row * MLPD + cc] = f2b(g);
    }
}

__global__ __launch_bounds__(256) void k_mlp2(const unsigned short* __restrict__ h1,
        const unsigned short* __restrict__ wT, const float* __restrict__ b2,
        float* __restrict__ seq){
    __shared__ unsigned short A_s[64*72];
    __shared__ unsigned short B_s[64*72];
    int n0 = blockIdx.x * 64, m0 = blockIdx.y * 64;
    int sp = blockIdx.z;
    int wave = threadIdx.x >> 6, lane = threadIdx.x & 63;
    int wm = wave >> 1, wn = wave & 1, lm = lane & 15, lq = lane >> 4;
    floatx4 z = {0.f, 0.f, 0.f, 0.f};
    floatx4 acc[2][2] = {{z, z}, {z, z}};
    for (int c = 0; c < 8; ++c){
        int kk = sp * 512 + c * 64;
        __syncthreads();
        stage64(h1 + (size_t)m0 * MLPD + kk, MLPD, A_s);
        stage64(wT + (size_t)n0 * MLPD + kk, MLPD, B_s);
        __syncthreads();
        mma_chunk(A_s, 72, B_s, acc, wm, wn, lm, lq);
    }
    #pragma unroll
    for (int fm = 0; fm < 2; ++fm)
    #pragma unroll
    for (int fn = 0; fn < 2; ++fn)
    #pragma unroll
    for (int i = 0; i < 4; ++i){
        int row = m0 + wm*32 + fm*16 + lq*4 + i;
        int cc = n0 + wn*32 + fn*16 + lm;
        float v = acc[fm][fn][i];
        if (sp == 0) v += b2[cc];
        atomicAdd(&seq[(size_t)row * DIM + cc], v);
    }
}

__global__ __launch_bounds__(256) void k_flush(const float* __restrict__ seq,
        float* __restrict__ out){
    int idx = blockIdx.x * 256 + threadIdx.x;
    int b = idx >> 9, c = idx & 511;
    out[idx] = seq[(size_t)(2*b + 1) * DIM + c];
}

// ---------------- host launch ----------------
extern "C" void kernel_launch(void* const* d_in, const int* in_sizes, int n_in,
                              void* d_out, int out_size, void* d_ws, size_t ws_size,
                              hipStream_t stream){
    const float* obs  = (const float*)d_in[0];
    const int*   dones= (const int*)d_in[1];
    const float* mem0 = (const float*)d_in[2];
    const float* memk = (const float*)d_in[3];
    const float* ln1s = (const float*)d_in[4];
    const float* ln1b = (const float*)d_in[5];
    const float* wq   = (const float*)d_in[6];
    const float* bq   = (const float*)d_in[7];
    const float* wk   = (const float*)d_in[8];
    const float* bk   = (const float*)d_in[9];
    const float* wv   = (const float*)d_in[10];
    const float* bv   = (const float*)d_in[11];
    const float* wo   = (const float*)d_in[12];
    const float* bo   = (const float*)d_in[13];
    const float* ln2s = (const float*)d_in[14];
    const float* ln2b = (const float*)d_in[15];
    const float* w1   = (const float*)d_in[16];
    const float* b1   = (const float*)d_in[17];
    const float* w2   = (const float*)d_in[18];
    const float* b2   = (const float*)d_in[19];
    float* out = (float*)d_out;

    char* ws = (char*)d_ws;
    unsigned short* memkT = (unsigned short*)(ws + 0);          // 512*512 bf16
    unsigned short* qkvT  = (unsigned short*)(ws + 524288);     // 4*1536*512
    unsigned short* woT   = (unsigned short*)(ws + 6815744);    // 4*512*512
    unsigned short* w1T   = (unsigned short*)(ws + 8912896);    // 4*2048*512
    unsigned short* w2T   = (unsigned short*)(ws + 17301504);   // 4*512*2048
    float* seq0           = (float*)(ws + 25690112);            // 512*512 f32
    float* seq1           = (float*)(ws + 26738688);            // 512*512 f32
    unsigned short* qkv   = (unsigned short*)(ws + 27787264);   // 512*1536 bf16
    unsigned short* h1    = (unsigned short*)(ws + 29360128);   // 512*2048 bf16
    // total 31457280 bytes

    dim3 blk(256);
    k_transpose<<<dim3(8, 8), blk, 0, stream>>>(memk, memkT, 512, 512);
    for (int l = 0; l < NLAY; ++l){
        k_transpose<<<dim3(8, 8), blk, 0, stream>>>(wq + (size_t)l*262144, qkvT + (size_t)l*786432,          512, 512);
        k_transpose<<<dim3(8, 8), blk, 0, stream>>>(wk + (size_t)l*262144, qkvT + (size_t)l*786432 + 262144, 512, 512);
        k_transpose<<<dim3(8, 8), blk, 0, stream>>>(wv + (size_t)l*262144, qkvT + (size_t)l*786432 + 524288, 512, 512);
        k_transpose<<<dim3(8, 8), blk, 0, stream>>>(wo + (size_t)l*262144, woT + (size_t)l*262144,           512, 512);
        k_transpose<<<dim3(8, 32), blk, 0, stream>>>(w1 + (size_t)l*1048576, w1T + (size_t)l*1048576,        512, 2048);
        k_transpose<<<dim3(32, 8), blk, 0, stream>>>(w2 + (size_t)l*1048576, w2T + (size_t)l*1048576,        2048, 512);
    }

    P prm;
    prm.obs = obs; prm.dones = dones; prm.mem0 = mem0;
    prm.memkT = memkT; prm.qkvT = qkvT; prm.woT = woT; prm.w1T = w1T; prm.w2T = w2T;
    prm.ln1s = ln1s; prm.ln1b = ln1b; prm.bq = bq; prm.bk = bk; prm.bv = bv;
    prm.bo = bo; prm.ln2s = ln2s; prm.ln2b = ln2b; prm.b1 = b1; prm.b2 = b2;
    prm.seq0 = seq0; prm.seq1 = seq1; prm.qkv = qkv; prm.h1 = h1; prm.out = out;

    void* kargs[] = { (void*)&prm };
    hipError_t ce = hipLaunchCooperativeKernel((const void*)k_persist,
            dim3(GRID), dim3(256), kargs, 0, stream);

    if (ce != hipSuccess){
        // fallback: original per-phase launch sequence
        for (int t = 0; t < NT; ++t){
            float* scur  = (t & 1) ? seq1 : seq0;
            float* sprev = (t & 1) ? seq0 : seq1;
            k_memgemm<<<dim3(8, 4), blk, 0, stream>>>(t,
                    obs + (size_t)t * NB * DIM, dones + t * NB, mem0,
                    sprev, memkT, scur,
                    out + (size_t)(t > 0 ? t - 1 : 0) * NB * DIM);
            for (int l = 0; l < NLAY; ++l){
                k_qkv<<<dim3(24, 8), blk, 0, stream>>>(scur, qkvT + (size_t)l*786432,
                        bq + l*512, bk + l*512, bv + l*512, ln1s + l*512, ln1b + l*512, qkv);
                k_attno<<<dim3(8, 8, 2), blk, 0, stream>>>(qkv, woT + (size_t)l*262144, bo + l*512, scur);
                k_mlp1<<<dim3(32, 8, 1), blk, 0, stream>>>(scur, w1T + (size_t)l*1048576, b1 + l*2048,
                        ln2s + l*512, ln2b + l*512, h1);
                k_mlp2<<<dim3(8, 8, 4), blk, 0, stream>>>(h1, w2T + (size_t)l*1048576, b2 + l*512, scur);
            }
        }
        k_flush<<<dim3(512), blk, 0, stream>>>(((NT - 1) & 1) ? seq1 : seq0,
                out + (size_t)(NT - 1) * NB * DIM);
    }
}

// Round 2
// 220453.271 us; speedup vs baseline: 1.3634x; 1.3634x over previous
//
#include <hip/hip_runtime.h>

#define DIM   512
#define QKVW  1536
#define MLPD  2048
#define NB    256
#define NT    256
#define NLAY  4
#define GRID  256

typedef __attribute__((ext_vector_type(8))) short short8;
typedef __attribute__((ext_vector_type(4))) float floatx4;

static __device__ __forceinline__ float b2f(unsigned short x){
    return __uint_as_float(((unsigned int)x) << 16);
}
static __device__ __forceinline__ unsigned short f2b(float f){
    unsigned int u = __float_as_uint(f);
    u += 0x7fffu + ((u >> 16) & 1u);
    return (unsigned short)(u >> 16);
}

// ---------------- one-time weight transpose+cast: src f32[K][N] -> dst bf16[N][K] ----------------
__global__ __launch_bounds__(256) void k_transpose(const float* __restrict__ src,
        unsigned short* __restrict__ dst, int K, int N){
    __shared__ unsigned short tile[64][65];
    int r0 = blockIdx.x * 64, c0 = blockIdx.y * 64;
    int tx = threadIdx.x & 63, ty = threadIdx.x >> 6;
    #pragma unroll
    for (int i = 0; i < 16; ++i){
        int r = ty + 4 * i;
        tile[r][tx] = f2b(src[(size_t)(r0 + r) * N + c0 + tx]);
    }
    __syncthreads();
    #pragma unroll
    for (int i = 0; i < 16; ++i){
        int r = ty + 4 * i;
        dst[(size_t)(c0 + r) * K + r0 + tx] = tile[tx][r];
    }
}

// ---------------- shared GEMM building blocks ----------------
// stage a 64x64 bf16 chunk into lds[64][72] (fallback path only)
static __device__ __forceinline__ void stage64(const unsigned short* __restrict__ g,
        int rstride, unsigned short* lds){
    int r = threadIdx.x >> 2, s = threadIdx.x & 3;
    const int4* src = (const int4*)(g + (size_t)r * rstride + s * 16);
    int4* dst = (int4*)(lds + r * 72 + s * 16);
    dst[0] = src[0];
    dst[1] = src[1];
}

// MFMA 64x64 over K=64: A from LDS (stride astride), B from LDS (stride 72)
static __device__ __forceinline__ void mma_chunk(const unsigned short* __restrict__ A_s, int astride,
        const unsigned short* __restrict__ B_s, floatx4 acc[2][2], int wm, int wn, int lm, int lq){
    #pragma unroll
    for (int ks = 0; ks < 2; ++ks){
        short8 a0 = *(const short8*)(A_s + (wm*32 + lm) * astride + ks*32 + lq*8);
        short8 a1 = *(const short8*)(A_s + (wm*32 + 16 + lm) * astride + ks*32 + lq*8);
        short8 b0 = *(const short8*)(B_s + (wn*32 + lm) * 72 + ks*32 + lq*8);
        short8 b1 = *(const short8*)(B_s + (wn*32 + 16 + lm) * 72 + ks*32 + lq*8);
        acc[0][0] = __builtin_amdgcn_mfma_f32_16x16x32_bf16(a0, b0, acc[0][0], 0, 0, 0);
        acc[0][1] = __builtin_amdgcn_mfma_f32_16x16x32_bf16(a0, b1, acc[0][1], 0, 0, 0);
        acc[1][0] = __builtin_amdgcn_mfma_f32_16x16x32_bf16(a1, b0, acc[1][0], 0, 0, 0);
        acc[1][1] = __builtin_amdgcn_mfma_f32_16x16x32_bf16(a1, b1, acc[1][1], 0, 0, 0);
    }
}

// MFMA 64x64 over K=64: A from LDS, B directly from global (weight is [out][K] bf16, L2-hot)
static __device__ __forceinline__ void mma_g(const unsigned short* __restrict__ A_s, int astride,
        const unsigned short* __restrict__ Bg, int bstride, floatx4 acc[2][2], int wm, int wn, int lm, int lq){
    #pragma unroll
    for (int ks = 0; ks < 2; ++ks){
        short8 a0 = *(const short8*)(A_s + (wm*32 + lm) * astride + ks*32 + lq*8);
        short8 a1 = *(const short8*)(A_s + (wm*32 + 16 + lm) * astride + ks*32 + lq*8);
        short8 b0 = *(const short8*)(Bg + (size_t)(wn*32 + lm) * bstride + ks*32 + lq*8);
        short8 b1 = *(const short8*)(Bg + (size_t)(wn*32 + 16 + lm) * bstride + ks*32 + lq*8);
        acc[0][0] = __builtin_amdgcn_mfma_f32_16x16x32_bf16(a0, b0, acc[0][0], 0, 0, 0);
        acc[0][1] = __builtin_amdgcn_mfma_f32_16x16x32_bf16(a0, b1, acc[0][1], 0, 0, 0);
        acc[1][0] = __builtin_amdgcn_mfma_f32_16x16x32_bf16(a1, b0, acc[1][0], 0, 0, 0);
        acc[1][1] = __builtin_amdgcn_mfma_f32_16x16x32_bf16(a1, b1, acc[1][1], 0, 0, 0);
    }
}

static __device__ __forceinline__ void ln_stats(const float* __restrict__ seq, int row0,
        float* mu_s, float* rs_s, float* red){
    int r = threadIdx.x >> 2, p = threadIdx.x & 3;
    const float* s = seq + (size_t)(row0 + r) * DIM + p * 128;
    float sm = 0.f, ss = 0.f;
    for (int k = 0; k < 128; k += 4){
        float4 v = *(const float4*)(s + k);
        sm += v.x + v.y + v.z + v.w;
        ss += v.x*v.x + v.y*v.y + v.z*v.z + v.w*v.w;
    }
    red[r*8 + p] = sm;
    red[r*8 + 4 + p] = ss;
    __syncthreads();
    if (threadIdx.x < 64){
        int rr = threadIdx.x;
        float s4 = red[rr*8+0] + red[rr*8+1] + red[rr*8+2] + red[rr*8+3];
        float q4 = red[rr*8+4] + red[rr*8+5] + red[rr*8+6] + red[rr*8+7];
        float mu = s4 * (1.f / DIM);
        float var = q4 * (1.f / DIM) - mu * mu;
        mu_s[rr] = mu;
        rs_s[rr] = rsqrtf(var + 1e-6f);
    }
    __syncthreads();
}

static __device__ __forceinline__ void stageA_ln(const float* __restrict__ seq, int row0, int kk,
        const float* __restrict__ lns, const float* __restrict__ lnb,
        const float* mu_s, const float* rs_s, unsigned short* lds){
    int r = threadIdx.x >> 2, s = threadIdx.x & 3;
    const float* src = seq + (size_t)(row0 + r) * DIM + kk + s * 16;
    float mu = mu_s[r], rs = rs_s[r];
    unsigned short tmp[16];
    #pragma unroll
    for (int j = 0; j < 16; ++j){
        float g = lns[kk + s*16 + j];
        float bb = lnb[kk + s*16 + j];
        tmp[j] = f2b((src[j] - mu) * rs * g + bb);
    }
    int4* dst = (int4*)(lds + r * 72 + s * 16);
    dst[0] = *(int4*)(tmp);
    dst[1] = *(int4*)(tmp + 8);
}

// ---------------- custom grid barrier (monotonic generation, agent scope) ----------------
static __device__ __forceinline__ void gbar(unsigned* bar, unsigned gen){
    __syncthreads();                      // drains all waves' vmem to L2
    if (threadIdx.x == 0){
        __builtin_amdgcn_fence(__ATOMIC_RELEASE, "agent");   // wb L2 (cross-XCD publish)
        unsigned arrived = __hip_atomic_fetch_add(&bar[0], 1u,
                __ATOMIC_RELAXED, __HIP_MEMORY_SCOPE_AGENT) + 1u;
        if (arrived == (unsigned)GRID * gen){
            __hip_atomic_store(&bar[16], gen, __ATOMIC_RELAXED, __HIP_MEMORY_SCOPE_AGENT);
        } else {
            while (__hip_atomic_load(&bar[16], __ATOMIC_RELAXED, __HIP_MEMORY_SCOPE_AGENT) < gen)
                __builtin_amdgcn_s_sleep(2);
        }
        __builtin_amdgcn_fence(__ATOMIC_ACQUIRE, "agent");   // inv L1+L2
    }
    __syncthreads();
}

__global__ __launch_bounds__(256) void k_zero(unsigned* p){
    if (threadIdx.x < 32) p[threadIdx.x] = 0;
}

// ---------------- persistent cooperative kernel ----------------
struct P {
    const float* obs; const int* dones; const float* mem0;
    const unsigned short* memkT;
    const unsigned short* qkvT; const unsigned short* woT;
    const unsigned short* w1T;  const unsigned short* w2T;
    const float *ln1s, *ln1b, *bq, *bk, *bv, *bo, *ln2s, *ln2b, *b1, *b2;
    float* seq0; float* seq1;
    float* out;
    unsigned* bar;
};

__global__ __launch_bounds__(256) void k_persist(P p){
    __shared__ __align__(16) char smem[46080];
    unsigned short* A_s  = (unsigned short*)smem;              // 9216 (also O_s)
    unsigned short* Q_s  = (unsigned short*)(smem + 9216);     // 9216
    unsigned short* K_s  = (unsigned short*)(smem + 18432);    // 9216
    unsigned short* V_s  = (unsigned short*)(smem + 27648);    // 9216
    unsigned short* h1_s = (unsigned short*)(smem + 9216);     // 64*264*2 = 33792 (P2 union)
    float* red   = (float*)(smem + 43008);                     // 2048
    float* mu_s  = (float*)(smem + 45056);                     // 256
    float* rs_s  = (float*)(smem + 45312);                     // 256
    float* p_lds = (float*)(smem + 45568);                     // 512

    const int bid  = blockIdx.x;
    const int wave = threadIdx.x >> 6, lane = threadIdx.x & 63;
    const int wm = wave >> 1, wn = wave & 1, lm = lane & 15, lq = lane >> 4;
    const floatx4 z = {0.f, 0.f, 0.f, 0.f};
    unsigned gen = 0;

    for (int t = 0; t < NT; ++t){
        float* scur  = (t & 1) ? p.seq1 : p.seq0;
        float* sprev = (t & 1) ? p.seq0 : p.seq1;
        const float* obs_t = p.obs + (size_t)t * NB * DIM;
        const int* dones_t = p.dones + t * NB;
        float* outprev = p.out + (size_t)(t > 0 ? t - 1 : 0) * NB * DIM;

        // ---- phase M: mem gating + mem_tok GEMM; build seq; emit out[t-1] ----
        if (bid < 32){
            int n0 = (bid & 7) * 64, m0 = (bid >> 3) * 64;   // m0 over batch
            floatx4 acc[2][2] = {{z, z}, {z, z}};
            for (int kk = 0; kk < DIM; kk += 64){
                __syncthreads();
                {
                    int r = threadIdx.x >> 2, s = threadIdx.x & 3;
                    int b = m0 + r;
                    int done = dones_t[b];
                    unsigned short tmp[16];
                    if (t == 0){
                        const float* src = p.mem0 + (size_t)b * DIM + kk + s * 16;
                        #pragma unroll
                        for (int j = 0; j < 16; ++j) tmp[j] = done ? (unsigned short)0 : f2b(src[j]);
                    } else {
                        const float* src = sprev + (size_t)(2*b + 1) * DIM + kk + s * 16;
                        #pragma unroll
                        for (int j = 0; j < 16; ++j){
                            float x = src[j];
                            if (n0 == 0) outprev[(size_t)b * DIM + kk + s*16 + j] = x;
                            tmp[j] = done ? (unsigned short)0 : f2b(x);
                        }
                    }
                    int4* dst = (int4*)(A_s + r * 72 + s * 16);
                    dst[0] = *(int4*)tmp;
                    dst[1] = *(int4*)(tmp + 8);
                }
                __syncthreads();
                mma_g(A_s, 72, p.memkT + (size_t)n0 * DIM + kk, DIM, acc, wm, wn, lm, lq);
            }
            #pragma unroll
            for (int fm = 0; fm < 2; ++fm)
            #pragma unroll
            for (int fn = 0; fn < 2; ++fn)
            #pragma unroll
            for (int i = 0; i < 4; ++i){
                int b = m0 + wm*32 + fm*16 + lq*4 + i;
                int c = n0 + wn*32 + fn*16 + lm;
                scur[(size_t)(2*b) * DIM + c] = acc[fm][fn][i];
                scur[(size_t)(2*b + 1) * DIM + c] = obs_t[(size_t)b * DIM + c];
            }
        }
        ++gen; gbar(p.bar, gen);

        for (int l = 0; l < NLAY; ++l){
            // ---- phase 1: LN1 + QKV(head) + attention + O-proj partial ----
            if (bid < 64){
                int m0 = (bid >> 3) * 64;          // token-row tile
                int h  = bid & 7;                  // head
                const unsigned short* wqkv = p.qkvT + (size_t)l * 786432;
                const float* lns = p.ln1s + l * DIM;
                const float* lnb = p.ln1b + l * DIM;
                ln_stats(scur, m0, mu_s, rs_s, red);
                floatx4 acc3[3][2][2] = {{{z,z},{z,z}},{{z,z},{z,z}},{{z,z},{z,z}}};
                for (int kk = 0; kk < DIM; kk += 64){
                    __syncthreads();
                    stageA_ln(scur, m0, kk, lns, lnb, mu_s, rs_s, A_s);
                    __syncthreads();
                    #pragma unroll
                    for (int sec = 0; sec < 3; ++sec)
                        mma_g(A_s, 72, wqkv + (size_t)(sec*512 + h*64) * DIM + kk, DIM,
                              acc3[sec], wm, wn, lm, lq);
                }
                // epilogue: +bias, write q/k/v tiles (bf16) to LDS
                {
                    const float* bql = p.bq + l*DIM + h*64;
                    const float* bkl = p.bk + l*DIM + h*64;
                    const float* bvl = p.bv + l*DIM + h*64;
                    __syncthreads();
                    #pragma unroll
                    for (int sec = 0; sec < 3; ++sec){
                        unsigned short* dstT = (sec == 0) ? Q_s : ((sec == 1) ? K_s : V_s);
                        const float* bias = (sec == 0) ? bql : ((sec == 1) ? bkl : bvl);
                        #pragma unroll
                        for (int fm = 0; fm < 2; ++fm)
                        #pragma unroll
                        for (int fn = 0; fn < 2; ++fn)
                        #pragma unroll
                        for (int i = 0; i < 4; ++i){
                            int row = wm*32 + fm*16 + lq*4 + i;
                            int col = wn*32 + fn*16 + lm;
                            dstT[row*72 + col] = f2b(acc3[sec][fm][fn][i] + bias[col]);
                        }
                    }
                }
                __syncthreads();
                // attention scores + softmax (rows = tokens: row=2b+tok)
                if (threadIdx.x < 64){
                    int row = threadIdx.x;             // local seq row
                    int b2 = row & ~1;                 // row of token 0 for this batch
                    const unsigned short* qrow = Q_s + row*72;
                    const unsigned short* k0 = K_s + b2*72;
                    const unsigned short* k1 = k0 + 72;
                    float s0 = 0.f, s1 = 0.f;
                    #pragma unroll
                    for (int d8 = 0; d8 < 8; ++d8){
                        short8 qa = *(const short8*)(qrow + d8*8);
                        short8 ka = *(const short8*)(k0 + d8*8);
                        short8 kb = *(const short8*)(k1 + d8*8);
                        #pragma unroll
                        for (int j = 0; j < 8; ++j){
                            float q = b2f((unsigned short)qa[j]);
                            s0 += q * b2f((unsigned short)ka[j]);
                            s1 += q * b2f((unsigned short)kb[j]);
                        }
                    }
                    s0 *= 0.125f; s1 *= 0.125f;
                    float mx = fmaxf(s0, s1);
                    float e0 = __expf(s0 - mx), e1 = __expf(s1 - mx);
                    float inv = 1.f / (e0 + e1);
                    p_lds[row*2 + 0] = e0 * inv;
                    p_lds[row*2 + 1] = e1 * inv;
                }
                __syncthreads();
                // O = P @ V  (write bf16 to A_s area, stride 72)
                if (threadIdx.x < 128){
                    int b_l = threadIdx.x >> 2, seg = threadIdx.x & 3;
                    const unsigned short* v0 = V_s + (2*b_l) * 72 + seg*16;
                    const unsigned short* v1 = v0 + 72;
                    #pragma unroll
                    for (int r = 0; r < 2; ++r){
                        int row = 2*b_l + r;
                        float p0 = p_lds[row*2 + 0], p1 = p_lds[row*2 + 1];
                        unsigned short o[16];
                        #pragma unroll
                        for (int j = 0; j < 16; ++j)
                            o[j] = f2b(p0 * b2f(v0[j]) + p1 * b2f(v1[j]));
                        int4* dst = (int4*)(A_s + row*72 + seg*16);
                        dst[0] = *(int4*)o;
                        dst[1] = *(int4*)(o + 8);
                    }
                }
                __syncthreads();
                // O-proj: out 64x512 partial (K = this head's 64 dims), atomicAdd residual
                {
                    const unsigned short* wol = p.woT + (size_t)l * 262144;
                    const float* bol = p.bo + l * DIM;
                    for (int n = 0; n < 8; ++n){
                        floatx4 acc[2][2] = {{z, z}, {z, z}};
                        mma_g(A_s, 72, wol + (size_t)(n*64) * DIM + h*64, DIM, acc, wm, wn, lm, lq);
                        #pragma unroll
                        for (int fm = 0; fm < 2; ++fm)
                        #pragma unroll
                        for (int fn = 0; fn < 2; ++fn)
                        #pragma unroll
                        for (int i = 0; i < 4; ++i){
                            int row = m0 + wm*32 + fm*16 + lq*4 + i;
                            int cc = n*64 + wn*32 + fn*16 + lm;
                            float v = acc[fm][fn][i];
                            if (h == 0) v += bol[cc];
                            atomicAdd(&scur[(size_t)row * DIM + cc], v);
                        }
                    }
                }
            }
            ++gen; gbar(p.bar, gen);

            // ---- phase 2: LN2 + MLP1 + gelu + MLP2 partial ----
            if (bid < 64){
                int m0 = (bid >> 3) * 64;
                int c0 = (bid & 7) * 256;          // h1 column slice
                const unsigned short* w1l = p.w1T + (size_t)l * 1048576;
                const unsigned short* w2l = p.w2T + (size_t)l * 1048576;
                const float* lns = p.ln2s + l * DIM;
                const float* lnb = p.ln2b + l * DIM;
                const float* b1l = p.b1 + l * MLPD;
                ln_stats(scur, m0, mu_s, rs_s, red);
                floatx4 acc4[4][2][2] = {{{z,z},{z,z}},{{z,z},{z,z}},{{z,z},{z,z}},{{z,z},{z,z}}};
                for (int kk = 0; kk < DIM; kk += 64){
                    __syncthreads();
                    stageA_ln(scur, m0, kk, lns, lnb, mu_s, rs_s, A_s);
                    __syncthreads();
                    #pragma unroll
                    for (int ns = 0; ns < 4; ++ns)
                        mma_g(A_s, 72, w1l + (size_t)(c0 + ns*64) * DIM + kk, DIM,
                              acc4[ns], wm, wn, lm, lq);
                }
                __syncthreads();
                // bias + gelu -> h1 tile (bf16, stride 264)
                #pragma unroll
                for (int ns = 0; ns < 4; ++ns)
                #pragma unroll
                for (int fm = 0; fm < 2; ++fm)
                #pragma unroll
                for (int fn = 0; fn < 2; ++fn)
                #pragma unroll
                for (int i = 0; i < 4; ++i){
                    int row = wm*32 + fm*16 + lq*4 + i;
                    int cl = ns*64 + wn*32 + fn*16 + lm;
                    float v = acc4[ns][fm][fn][i] + b1l[c0 + cl];
                    float g = 0.5f * v * (1.f + tanhf(0.7978845608028654f * (v + 0.044715f * v * v * v)));
                    h1_s[row*264 + cl] = f2b(g);
                }
                __syncthreads();
                // MLP2: out 64x512 partial over K = this 256-slice, atomicAdd residual
                {
                    const float* b2l = p.b2 + l * DIM;
                    for (int n = 0; n < 8; ++n){
                        floatx4 acc[2][2] = {{z, z}, {z, z}};
                        #pragma unroll
                        for (int c = 0; c < 4; ++c)
                            mma_g(h1_s + c*64, 264, w2l + (size_t)(n*64) * MLPD + c0 + c*64, MLPD,
                                  acc, wm, wn, lm, lq);
                        #pragma unroll
                        for (int fm = 0; fm < 2; ++fm)
                        #pragma unroll
                        for (int fn = 0; fn < 2; ++fn)
                        #pragma unroll
                        for (int i = 0; i < 4; ++i){
                            int row = m0 + wm*32 + fm*16 + lq*4 + i;
                            int cc = n*64 + wn*32 + fn*16 + lm;
                            float v = acc[fm][fn][i];
                            if (c0 == 0) v += b2l[cc];
                            atomicAdd(&scur[(size_t)row * DIM + cc], v);
                        }
                    }
                }
            }
            ++gen; gbar(p.bar, gen);
        }
    }

    // ---- flush out[T-1] ----
    {
        const float* sfin = ((NT - 1) & 1) ? p.seq1 : p.seq0;
        float* o = p.out + (size_t)(NT - 1) * NB * DIM;
        for (int idx = bid * 256 + threadIdx.x; idx < NB * DIM; idx += GRID * 256){
            int b = idx >> 9, c = idx & 511;
            o[idx] = sfin[(size_t)(2*b + 1) * DIM + c];
        }
    }
}

// ---------------- fallback per-phase kernels (used only if cooperative launch fails) ----------------
__global__ __launch_bounds__(256) void k_memgemm(int t,
        const float* __restrict__ obs, const int* __restrict__ dones,
        const float* __restrict__ mem0, const float* __restrict__ seqprev,
        const unsigned short* __restrict__ wT, float* __restrict__ seqcur,
        float* __restrict__ outprev){
    __shared__ unsigned short A_s[64*72];
    __shared__ unsigned short B_s[64*72];
    int n0 = blockIdx.x * 64, m0 = blockIdx.y * 64;
    int wave = threadIdx.x >> 6, lane = threadIdx.x & 63;
    int wm = wave >> 1, wn = wave & 1, lm = lane & 15, lq = lane >> 4;
    floatx4 z = {0.f, 0.f, 0.f, 0.f};
    floatx4 acc[2][2] = {{z, z}, {z, z}};
    for (int kk = 0; kk < DIM; kk += 64){
        __syncthreads();
        {
            int r = threadIdx.x >> 2, s = threadIdx.x & 3;
            int b = m0 + r;
            int done = dones[b];
            unsigned short tmp[16];
            if (t == 0){
                const float* src = mem0 + (size_t)b * DIM + kk + s * 16;
                #pragma unroll
                for (int j = 0; j < 16; ++j) tmp[j] = done ? (unsigned short)0 : f2b(src[j]);
            } else {
                const float* src = seqprev + (size_t)(2*b + 1) * DIM + kk + s * 16;
                #pragma unroll
                for (int j = 0; j < 16; ++j){
                    float x = src[j];
                    if (blockIdx.x == 0) outprev[(size_t)b * DIM + kk + s*16 + j] = x;
                    tmp[j] = done ? (unsigned short)0 : f2b(x);
                }
            }
            int4* dst = (int4*)(A_s + r * 72 + s * 16);
            dst[0] = *(int4*)tmp;
            dst[1] = *(int4*)(tmp + 8);
        }
        stage64(wT + (size_t)n0 * DIM + kk, DIM, B_s);
        __syncthreads();
        mma_chunk(A_s, 72, B_s, acc, wm, wn, lm, lq);
    }
    #pragma unroll
    for (int fm = 0; fm < 2; ++fm)
    #pragma unroll
    for (int fn = 0; fn < 2; ++fn)
    #pragma unroll
    for (int i = 0; i < 4; ++i){
        int b = m0 + wm*32 + fm*16 + lq*4 + i;
        int c = n0 + wn*32 + fn*16 + lm;
        seqcur[(size_t)(2*b) * DIM + c] = acc[fm][fn][i];
        seqcur[(size_t)(2*b + 1) * DIM + c] = obs[(size_t)b * DIM + c];
    }
}

__global__ __launch_bounds__(256) void k_qkv(const float* __restrict__ seq,
        const unsigned short* __restrict__ wT,
        const float* __restrict__ bq, const float* __restrict__ bk,
        const float* __restrict__ bv,
        const float* __restrict__ lns, const float* __restrict__ lnb,
        unsigned short* __restrict__ qkv){
    __shared__ unsigned short A_s[64*72];
    __shared__ unsigned short B_s[64*72];
    __shared__ float red[64*8];
    __shared__ float mu_s[64], rs_s[64];
    int n0 = blockIdx.x * 64, m0 = blockIdx.y * 64;
    ln_stats(seq, m0, mu_s, rs_s, red);
    int wave = threadIdx.x >> 6, lane = threadIdx.x & 63;
    int wm = wave >> 1, wn = wave & 1, lm = lane & 15, lq = lane >> 4;
    floatx4 z = {0.f, 0.f, 0.f, 0.f};
    floatx4 acc[2][2] = {{z, z}, {z, z}};
    for (int kk = 0; kk < DIM; kk += 64){
        __syncthreads();
        stageA_ln(seq, m0, kk, lns, lnb, mu_s, rs_s, A_s);
        stage64(wT + (size_t)n0 * DIM + kk, DIM, B_s);
        __syncthreads();
        mma_chunk(A_s, 72, B_s, acc, wm, wn, lm, lq);
    }
    int sec = n0 >> 9;
    const float* bias = (sec == 0) ? bq : ((sec == 1) ? bk : bv);
    int nsec = n0 & 511;
    #pragma unroll
    for (int fm = 0; fm < 2; ++fm)
    #pragma unroll
    for (int fn = 0; fn < 2; ++fn)
    #pragma unroll
    for (int i = 0; i < 4; ++i){
        int row = m0 + wm*32 + fm*16 + lq*4 + i;
        int cl = wn*32 + fn*16 + lm;
        float v = acc[fm][fn][i] + bias[nsec + cl];
        qkv[(size_t)row * QKVW + n0 + cl] = f2b(v);
    }
}

__global__ __launch_bounds__(256) void k_attno(const unsigned short* __restrict__ qkv,
        const unsigned short* __restrict__ wT,
        const float* __restrict__ bo, float* __restrict__ seq){
    __shared__ unsigned short O_s[64*264];
    __shared__ unsigned short B_s[64*72];
    int n0 = blockIdx.x * 64, m0 = blockIdx.y * 64;
    int sp = blockIdx.z;
    if (threadIdx.x < 128){
        int b_l = threadIdx.x >> 2, h_l = threadIdx.x & 3;
        int h = sp * 4 + h_l;
        const unsigned short* q0 = qkv + (size_t)(m0 + 2*b_l) * QKVW + h * 64;
        const unsigned short* q1 = q0 + QKVW;
        const unsigned short* k0p = q0 + 512;
        const unsigned short* k1p = k0p + QKVW;
        const unsigned short* v0p = q0 + 1024;
        const unsigned short* v1p = v0p + QKVW;
        float s00 = 0, s01 = 0, s10 = 0, s11 = 0;
        for (int f8 = 0; f8 < 8; ++f8){
            short8 a0 = *(const short8*)(q0 + f8*8);
            short8 a1 = *(const short8*)(q1 + f8*8);
            short8 c0 = *(const short8*)(k0p + f8*8);
            short8 c1 = *(const short8*)(k1p + f8*8);
            #pragma unroll
            for (int j = 0; j < 8; ++j){
                float qa = b2f((unsigned short)a0[j]);
                float qb = b2f((unsigned short)a1[j]);
                float ka = b2f((unsigned short)c0[j]);
                float kb = b2f((unsigned short)c1[j]);
                s00 += qa*ka; s01 += qa*kb; s10 += qb*ka; s11 += qb*kb;
            }
        }
        s00 *= 0.125f; s01 *= 0.125f; s10 *= 0.125f; s11 *= 0.125f;
        float m0v = fmaxf(s00, s01), m1v = fmaxf(s10, s11);
        float e00 = __expf(s00 - m0v), e01 = __expf(s01 - m0v);
        float e10 = __expf(s10 - m1v), e11 = __expf(s11 - m1v);
        float i0 = 1.f / (e00 + e01), i1 = 1.f / (e10 + e11);
        float p00 = e00*i0, p01 = e01*i0, p10 = e10*i1, p11 = e11*i1;
        for (int f8 = 0; f8 < 8; ++f8){
            short8 va = *(const short8*)(v0p + f8*8);
            short8 vb = *(const short8*)(v1p + f8*8);
            unsigned short o0[8], o1[8];
            #pragma unroll
            for (int j = 0; j < 8; ++j){
                float x0 = b2f((unsigned short)va[j]);
                float x1 = b2f((unsigned short)vb[j]);
                o0[j] = f2b(p00*x0 + p01*x1);
                o1[j] = f2b(p10*x0 + p11*x1);
            }
            *(int4*)(O_s + (2*b_l) * 264 + h_l*64 + f8*8) = *(int4*)o0;
            *(int4*)(O_s + (2*b_l + 1) * 264 + h_l*64 + f8*8) = *(int4*)o1;
        }
    }
    int wave = threadIdx.x >> 6, lane = threadIdx.x & 63;
    int wm = wave >> 1, wn = wave & 1, lm = lane & 15, lq = lane >> 4;
    floatx4 z = {0.f, 0.f, 0.f, 0.f};
    floatx4 acc[2][2] = {{z, z}, {z, z}};
    for (int c = 0; c < 4; ++c){
        int kkg = sp * 256 + c * 64;
        __syncthreads();
        stage64(wT + (size_t)n0 * DIM + kkg, DIM, B_s);
        __syncthreads();
        mma_chunk(O_s + c * 64, 264, B_s, acc, wm, wn, lm, lq);
    }
    #pragma unroll
    for (int fm = 0; fm < 2; ++fm)
    #pragma unroll
    for (int fn = 0; fn < 2; ++fn)
    #pragma unroll
    for (int i = 0; i < 4; ++i){
        int row = m0 + wm*32 + fm*16 + lq*4 + i;
        int cc = n0 + wn*32 + fn*16 + lm;
        float v = acc[fm][fn][i];
        if (sp == 0) v += bo[cc];
        atomicAdd(&seq[(size_t)row * DIM + cc], v);
    }
}

__global__ __launch_bounds__(256) void k_mlp1(const float* __restrict__ seq,
        const unsigned short* __restrict__ wT, const float* __restrict__ b1,
        const float* __restrict__ lns, const float* __restrict__ lnb,
        unsigned short* __restrict__ h1){
    __shared__ unsigned short A_s[64*72];
    __shared__ unsigned short B_s[64*72];
    __shared__ float red[64*8];
    __shared__ float mu_s[64], rs_s[64];
    int n0 = blockIdx.x * 64, m0 = blockIdx.y * 64;
    ln_stats(seq, m0, mu_s, rs_s, red);
    int wave = threadIdx.x >> 6, lane = threadIdx.x & 63;
    int wm = wave >> 1, wn = wave & 1, lm = lane & 15, lq = lane >> 4;
    floatx4 z = {0.f, 0.f, 0.f, 0.f};
    floatx4 acc[2][2] = {{z, z}, {z, z}};
    for (int kk = 0; kk < DIM; kk += 64){
        __syncthreads();
        stageA_ln(seq, m0, kk, lns, lnb, mu_s, rs_s, A_s);
        stage64(wT + (size_t)n0 * DIM + kk, DIM, B_s);
        __syncthreads();
        mma_chunk(A_s, 72, B_s, acc, wm, wn, lm, lq);
    }
    #pragma unroll
    for (int fm = 0; fm < 2; ++fm)
    #pragma unroll
    for (int fn = 0; fn < 2; ++fn)
    #pragma unroll
    for (int i = 0; i < 4; ++i){
        int row = m0 + wm*32 + fm*16 + lq*4 + i;
        int cc = n0 + wn*32 + fn*16 + lm;
        float v = acc[fm][fn][i] + b1[cc];
        float g = 0.5f * v * (1.f + tanhf(0.7978845608028654f * (v + 0.044715f * v * v * v)));
        h1[(size_t)row * MLPD + cc] = f2b(g);
    }
}

__global__ __launch_bounds__(256) void k_mlp2(const unsigned short* __restrict__ h1,
        const unsigned short* __restrict__ wT, const float* __restrict__ b2,
        float* __restrict__ seq){
    __shared__ unsigned short A_s[64*72];
    __shared__ unsigned short B_s[64*72];
    int n0 = blockIdx.x * 64, m0 = blockIdx.y * 64;
    int sp = blockIdx.z;
    int wave = threadIdx.x >> 6, lane = threadIdx.x & 63;
    int wm = wave >> 1, wn = wave & 1, lm = lane & 15, lq = lane >> 4;
    floatx4 z = {0.f, 0.f, 0.f, 0.f};
    floatx4 acc[2][2] = {{z, z}, {z, z}};
    for (int c = 0; c < 8; ++c){
        int kk = sp * 512 + c * 64;
        __syncthreads();
        stage64(h1 + (size_t)m0 * MLPD + kk, MLPD, A_s);
        stage64(wT + (size_t)n0 * MLPD + kk, MLPD, B_s);
        __syncthreads();
        mma_chunk(A_s, 72, B_s, acc, wm, wn, lm, lq);
    }
    #pragma unroll
    for (int fm = 0; fm < 2; ++fm)
    #pragma unroll
    for (int fn = 0; fn < 2; ++fn)
    #pragma unroll
    for (int i = 0; i < 4; ++i){
        int row = m0 + wm*32 + fm*16 + lq*4 + i;
        int cc = n0 + wn*32 + fn*16 + lm;
        float v = acc[fm][fn][i];
        if (sp == 0) v += b2[cc];
        atomicAdd(&seq[(size_t)row * DIM + cc], v);
    }
}

__global__ __launch_bounds__(256) void k_flush(const float* __restrict__ seq,
        float* __restrict__ out){
    int idx = blockIdx.x * 256 + threadIdx.x;
    int b = idx >> 9, c = idx & 511;
    out[idx] = seq[(size_t)(2*b + 1) * DIM + c];
}

// ---------------- host launch ----------------
extern "C" void kernel_launch(void* const* d_in, const int* in_sizes, int n_in,
                              void* d_out, int out_size, void* d_ws, size_t ws_size,
                              hipStream_t stream){
    const float* obs  = (const float*)d_in[0];
    const int*   dones= (const int*)d_in[1];
    const float* mem0 = (const float*)d_in[2];
    const float* memk = (const float*)d_in[3];
    const float* ln1s = (const float*)d_in[4];
    const float* ln1b = (const float*)d_in[5];
    const float* wq   = (const float*)d_in[6];
    const float* bq   = (const float*)d_in[7];
    const float* wk   = (const float*)d_in[8];
    const float* bk   = (const float*)d_in[9];
    const float* wv   = (const float*)d_in[10];
    const float* bv   = (const float*)d_in[11];
    const float* wo   = (const float*)d_in[12];
    const float* bo   = (const float*)d_in[13];
    const float* ln2s = (const float*)d_in[14];
    const float* ln2b = (const float*)d_in[15];
    const float* w1   = (const float*)d_in[16];
    const float* b1   = (const float*)d_in[17];
    const float* w2   = (const float*)d_in[18];
    const float* b2   = (const float*)d_in[19];
    float* out = (float*)d_out;

    char* ws = (char*)d_ws;
    unsigned short* memkT = (unsigned short*)(ws + 0);          // 512*512 bf16
    unsigned short* qkvT  = (unsigned short*)(ws + 524288);     // 4*1536*512
    unsigned short* woT   = (unsigned short*)(ws + 6815744);    // 4*512*512
    unsigned short* w1T   = (unsigned short*)(ws + 8912896);    // 4*2048*512
    unsigned short* w2T   = (unsigned short*)(ws + 17301504);   // 4*512*2048
    float* seq0           = (float*)(ws + 25690112);            // 512*512 f32
    float* seq1           = (float*)(ws + 26738688);            // 512*512 f32
    unsigned short* qkv   = (unsigned short*)(ws + 27787264);   // fallback only
    unsigned short* h1    = (unsigned short*)(ws + 29360128);   // fallback only
    unsigned* bar         = (unsigned*)(ws + 27787264);         // reused as barrier (persistent path)

    dim3 blk(256);
    k_transpose<<<dim3(8, 8), blk, 0, stream>>>(memk, memkT, 512, 512);
    for (int l = 0; l < NLAY; ++l){
        k_transpose<<<dim3(8, 8), blk, 0, stream>>>(wq + (size_t)l*262144, qkvT + (size_t)l*786432,          512, 512);
        k_transpose<<<dim3(8, 8), blk, 0, stream>>>(wk + (size_t)l*262144, qkvT + (size_t)l*786432 + 262144, 512, 512);
        k_transpose<<<dim3(8, 8), blk, 0, stream>>>(wv + (size_t)l*262144, qkvT + (size_t)l*786432 + 524288, 512, 512);
        k_transpose<<<dim3(8, 8), blk, 0, stream>>>(wo + (size_t)l*262144, woT + (size_t)l*262144,           512, 512);
        k_transpose<<<dim3(8, 32), blk, 0, stream>>>(w1 + (size_t)l*1048576, w1T + (size_t)l*1048576,        512, 2048);
        k_transpose<<<dim3(32, 8), blk, 0, stream>>>(w2 + (size_t)l*1048576, w2T + (size_t)l*1048576,        2048, 512);
    }
    k_zero<<<dim3(1), blk, 0, stream>>>(bar);

    P prm;
    prm.obs = obs; prm.dones = dones; prm.mem0 = mem0;
    prm.memkT = memkT; prm.qkvT = qkvT; prm.woT = woT; prm.w1T = w1T; prm.w2T = w2T;
    prm.ln1s = ln1s; prm.ln1b = ln1b; prm.bq = bq; prm.bk = bk; prm.bv = bv;
    prm.bo = bo; prm.ln2s = ln2s; prm.ln2b = ln2b; prm.b1 = b1; prm.b2 = b2;
    prm.seq0 = seq0; prm.seq1 = seq1; prm.out = out; prm.bar = bar;

    void* kargs[] = { (void*)&prm };
    hipError_t ce = hipLaunchCooperativeKernel((const void*)k_persist,
            dim3(GRID), dim3(256), kargs, 0, stream);

    if (ce != hipSuccess){
        // fallback: per-phase launch sequence
        for (int t = 0; t < NT; ++t){
            float* scur  = (t & 1) ? seq1 : seq0;
            float* sprev = (t & 1) ? seq0 : seq1;
            k_memgemm<<<dim3(8, 4), blk, 0, stream>>>(t,
                    obs + (size_t)t * NB * DIM, dones + t * NB, mem0,
                    sprev, memkT, scur,
                    out + (size_t)(t > 0 ? t - 1 : 0) * NB * DIM);
            for (int l = 0; l < NLAY; ++l){
                k_qkv<<<dim3(24, 8), blk, 0, stream>>>(scur, qkvT + (size_t)l*786432,
                        bq + l*512, bk + l*512, bv + l*512, ln1s + l*512, ln1b + l*512, qkv);
                k_attno<<<dim3(8, 8, 2), blk, 0, stream>>>(qkv, woT + (size_t)l*262144, bo + l*512, scur);
                k_mlp1<<<dim3(32, 8, 1), blk, 0, stream>>>(scur, w1T + (size_t)l*1048576, b1 + l*2048,
                        ln2s + l*512, ln2b + l*512, h1);
                k_mlp2<<<dim3(8, 8, 4), blk, 0, stream>>>(h1, w2T + (size_t)l*1048576, b2 + l*512, scur);
            }
        }
        k_flush<<<dim3(512), blk, 0, stream>>>(((NT - 1) & 1) ? seq1 : seq0,
                out + (size_t)(NT - 1) * NB * DIM);
    }
}

// Round 3
// 42471.671 us; speedup vs baseline: 7.0766x; 5.1906x over previous
//
#include <hip/hip_runtime.h>

#define DIM   512
#define QKVW  1536
#define MLPD  2048
#define NB    256
#define NT    256
#define NLAY  4
#define GRID  256
#define SEQP  514   // padded seq row stride (f32 words)
#define INVALID_PAIR 0xFFFFFFFFu

typedef __attribute__((ext_vector_type(8))) short short8;
typedef __attribute__((ext_vector_type(4))) float floatx4;

static __device__ __forceinline__ float b2f(unsigned short x){
    return __uint_as_float(((unsigned int)x) << 16);
}
static __device__ __forceinline__ unsigned short f2b(float f){
    unsigned int u = __float_as_uint(f);
    u += 0x7fffu + ((u >> 16) & 1u);
    return (unsigned short)(u >> 16);
}

// ---------------- one-time weight transpose+cast: src f32[K][N] -> dst bf16[N][K] ----------------
__global__ __launch_bounds__(256) void k_transpose(const float* __restrict__ src,
        unsigned short* __restrict__ dst, int K, int N){
    __shared__ unsigned short tile[64][65];
    int r0 = blockIdx.x * 64, c0 = blockIdx.y * 64;
    int tx = threadIdx.x & 63, ty = threadIdx.x >> 6;
    #pragma unroll
    for (int i = 0; i < 16; ++i){
        int r = ty + 4 * i;
        tile[r][tx] = f2b(src[(size_t)(r0 + r) * N + c0 + tx]);
    }
    __syncthreads();
    #pragma unroll
    for (int i = 0; i < 16; ++i){
        int r = ty + 4 * i;
        dst[(size_t)(c0 + r) * K + r0 + tx] = tile[tx][r];
    }
}

// ---------------- depth/round index precompute (single block) ----------------
__global__ __launch_bounds__(256) void k_depth(const int* __restrict__ dones,
        unsigned* __restrict__ offg, unsigned* __restrict__ idxg){
    __shared__ unsigned cnt[256];
    __shared__ unsigned pos[256];
    int b = threadIdx.x;
    cnt[b] = 0;
    __syncthreads();
    unsigned d = 0;
    for (int t = 0; t < NT; ++t){
        int done = dones[t * NB + b];
        d = (t == 0) ? 0u : (done ? 0u : d + 1u);
        atomicAdd(&cnt[d], 1u);
    }
    __syncthreads();
    if (b == 0){
        unsigned s = 0, mx = 0;
        for (int r = 0; r < 256; ++r){
            pos[r] = s;
            offg[r] = s;
            if (cnt[r]) mx = (unsigned)r;
            s += cnt[r];
        }
        offg[256] = s;
        offg[257] = mx + 1;   // number of rounds
    }
    __syncthreads();
    d = 0;
    for (int t = 0; t < NT; ++t){
        int done = dones[t * NB + b];
        d = (t == 0) ? 0u : (done ? 0u : d + 1u);
        unsigned q = atomicAdd(&pos[d], 1u);
        idxg[q] = (unsigned)(t * NB + b);
    }
}

__global__ __launch_bounds__(256) void k_zero(unsigned* p){
    if (threadIdx.x < 32) p[threadIdx.x] = 0;
}

// ---------------- grid barrier (monotonic generation, agent scope) ----------------
static __device__ __forceinline__ void gbar(unsigned* bar, unsigned gen){
    __syncthreads();
    if (threadIdx.x == 0){
        __builtin_amdgcn_fence(__ATOMIC_RELEASE, "agent");
        unsigned arrived = __hip_atomic_fetch_add(&bar[0], 1u,
                __ATOMIC_RELAXED, __HIP_MEMORY_SCOPE_AGENT) + 1u;
        if (arrived == (unsigned)GRID * gen){
            __hip_atomic_store(&bar[16], gen, __ATOMIC_RELAXED, __HIP_MEMORY_SCOPE_AGENT);
        } else {
            while (__hip_atomic_load(&bar[16], __ATOMIC_RELAXED, __HIP_MEMORY_SCOPE_AGENT) < gen)
                __builtin_amdgcn_s_sleep(32);
        }
        __builtin_amdgcn_fence(__ATOMIC_ACQUIRE, "agent");
    }
    __syncthreads();
}

// ---------------- MFMA helpers ----------------
// quadrant-style: wave (wm,wn) owns 32x32 of a 64x64 output; B from global [N][K]
static __device__ __forceinline__ void mma_g(const unsigned short* __restrict__ A_s, int astride,
        const unsigned short* __restrict__ Bg, int bstride, floatx4 acc[2][2], int wm, int wn, int lm, int lq){
    #pragma unroll
    for (int ks = 0; ks < 2; ++ks){
        short8 a0 = *(const short8*)(A_s + (wm*32 + lm) * astride + ks*32 + lq*8);
        short8 a1 = *(const short8*)(A_s + (wm*32 + 16 + lm) * astride + ks*32 + lq*8);
        short8 b0 = *(const short8*)(Bg + (size_t)(wn*32 + lm) * bstride + ks*32 + lq*8);
        short8 b1 = *(const short8*)(Bg + (size_t)(wn*32 + 16 + lm) * bstride + ks*32 + lq*8);
        acc[0][0] = __builtin_amdgcn_mfma_f32_16x16x32_bf16(a0, b0, acc[0][0], 0, 0, 0);
        acc[0][1] = __builtin_amdgcn_mfma_f32_16x16x32_bf16(a0, b1, acc[0][1], 0, 0, 0);
        acc[1][0] = __builtin_amdgcn_mfma_f32_16x16x32_bf16(a1, b0, acc[1][0], 0, 0, 0);
        acc[1][1] = __builtin_amdgcn_mfma_f32_16x16x32_bf16(a1, b1, acc[1][1], 0, 0, 0);
    }
}

// one wave computes full 64 rows x 64 cols over K=64: A [64][astride] LDS, B global [N][K]
static __device__ __forceinline__ void mma44(const unsigned short* __restrict__ A_s, int astride,
        const unsigned short* __restrict__ Bg, int bstride, floatx4 acc[4][4], int lm, int lq){
    #pragma unroll
    for (int ks = 0; ks < 2; ++ks){
        short8 a[4], b[4];
        #pragma unroll
        for (int m = 0; m < 4; ++m)
            a[m] = *(const short8*)(A_s + (m*16 + lm) * astride + ks*32 + lq*8);
        #pragma unroll
        for (int n = 0; n < 4; ++n)
            b[n] = *(const short8*)(Bg + (size_t)(n*16 + lm) * bstride + ks*32 + lq*8);
        #pragma unroll
        for (int m = 0; m < 4; ++m)
        #pragma unroll
        for (int n = 0; n < 4; ++n)
            acc[m][n] = __builtin_amdgcn_mfma_f32_16x16x32_bf16(a[m], b[n], acc[m][n], 0, 0, 0);
    }
}

// one wave computes 64 rows x 32 cols over K=64
static __device__ __forceinline__ void mma42(const unsigned short* __restrict__ A_s, int astride,
        const unsigned short* __restrict__ Bg, int bstride, floatx4 acc[4][2], int lm, int lq){
    #pragma unroll
    for (int ks = 0; ks < 2; ++ks){
        short8 a[4], b[2];
        #pragma unroll
        for (int m = 0; m < 4; ++m)
            a[m] = *(const short8*)(A_s + (m*16 + lm) * astride + ks*32 + lq*8);
        #pragma unroll
        for (int n = 0; n < 2; ++n)
            b[n] = *(const short8*)(Bg + (size_t)(n*16 + lm) * bstride + ks*32 + lq*8);
        #pragma unroll
        for (int m = 0; m < 4; ++m)
        #pragma unroll
        for (int n = 0; n < 2; ++n)
            acc[m][n] = __builtin_amdgcn_mfma_f32_16x16x32_bf16(a[m], b[n], acc[m][n], 0, 0, 0);
    }
}

// ---------------- LDS-seq LayerNorm helpers ----------------
static __device__ __forceinline__ void ln_statsL(const float* __restrict__ seqL,
        float* red, float* mu_s, float* rs_s){
    int r = threadIdx.x >> 2, p4 = threadIdx.x & 3;
    const float* s = seqL + r * SEQP + p4 * 128;
    float sm = 0.f, ss = 0.f;
    for (int k = 0; k < 128; k += 4){
        float4 v = *(const float4*)(s + k);
        sm += v.x + v.y + v.z + v.w;
        ss += v.x*v.x + v.y*v.y + v.z*v.z + v.w*v.w;
    }
    red[r*8 + p4] = sm;
    red[r*8 + 4 + p4] = ss;
    __syncthreads();
    if (threadIdx.x < 64){
        int rr = threadIdx.x;
        float s4 = red[rr*8+0] + red[rr*8+1] + red[rr*8+2] + red[rr*8+3];
        float q4 = red[rr*8+4] + red[rr*8+5] + red[rr*8+6] + red[rr*8+7];
        float mu = s4 * (1.f / DIM);
        float var = q4 * (1.f / DIM) - mu * mu;
        mu_s[rr] = mu;
        rs_s[rr] = rsqrtf(var + 1e-6f);
    }
    __syncthreads();
}

static __device__ __forceinline__ void stageA_lnL(const float* __restrict__ seqL, int kk,
        const float* __restrict__ lns, const float* __restrict__ lnb,
        const float* mu_s, const float* rs_s, unsigned short* A_s){
    int r = threadIdx.x >> 2, s = threadIdx.x & 3;
    const float* src = seqL + r * SEQP + kk + s * 16;
    float mu = mu_s[r], rs = rs_s[r];
    unsigned short tmp[16];
    #pragma unroll
    for (int j = 0; j < 16; ++j){
        float g = lns[kk + s*16 + j];
        float bb = lnb[kk + s*16 + j];
        tmp[j] = f2b((src[j] - mu) * rs * g + bb);
    }
    int4* dst = (int4*)(A_s + r * 72 + s * 16);
    dst[0] = *(int4*)(tmp);
    dst[1] = *(int4*)(tmp + 8);
}

// ---------------- persistent depth-parallel kernel ----------------
struct P {
    const float* obs; const int* dones; const float* mem0;
    const unsigned short* memkT;
    const unsigned short* qkvT; const unsigned short* woT;
    const unsigned short* w1T;  const unsigned short* w2T;
    const float *ln1s, *ln1b, *bq, *bk, *bv, *bo, *ln2s, *ln2b, *b1, *b2;
    const unsigned* off; const unsigned* idx;
    float* out;
    unsigned* bar;
};

// LDS layout (dynamic, 160384 bytes):
//   seqL  f32 [64][514]          @ 0       (131584)
//   A_s   bf16 [64][72]          @ 131584  (9216)   (also V_s; also P2 staging)
//   Q_s   bf16 [64][72]          @ 140800  (9216)   (also red; also O tile; also h1 lo)
//   K_s   bf16 [64][72]          @ 150016  (9216)   (also h1 hi)
//   h1_s  bf16 [64][136]         @ 140800  (17408)  (P2, aliases Q_s+K_s)
//   mu_s  f32 [64]               @ 159232
//   rs_s  f32 [64]               @ 159488
//   p_lds f32 [128]              @ 159744
//   pinfo u32 [32]               @ 160256
__global__ __launch_bounds__(256, 1) void k_persist(P p){
    extern __shared__ __align__(16) char smem[];
    float*          seqL  = (float*)smem;
    unsigned short* A_s   = (unsigned short*)(smem + 131584);
    unsigned short* Q_s   = (unsigned short*)(smem + 140800);
    unsigned short* K_s   = (unsigned short*)(smem + 150016);
    unsigned short* h1_s  = (unsigned short*)(smem + 140800);
    float*          redQ  = (float*)(smem + 140800);
    float*          mu_s  = (float*)(smem + 159232);
    float*          rs_s  = (float*)(smem + 159488);
    float*          p_lds = (float*)(smem + 159744);
    unsigned*       pinfo = (unsigned*)(smem + 160256);

    const int bid  = blockIdx.x;
    const int wave = threadIdx.x >> 6, lane = threadIdx.x & 63;
    const int wm = wave >> 1, wn = wave & 1, lm = lane & 15, lq = lane >> 4;
    const int w = wave;
    const floatx4 z = {0.f, 0.f, 0.f, 0.f};
    unsigned gen = 0;

    const int R = (int)p.off[257];

    for (int r = 0; r < R; ++r){
        unsigned base = p.off[r];
        unsigned cntr = p.off[r+1] - base;
        int tiles = (int)((cntr + 31u) >> 5);

        for (int tile = bid; tile < tiles; tile += GRID){
            __syncthreads();
            if (threadIdx.x < 32){
                unsigned q = base + (unsigned)tile * 32u + threadIdx.x;
                pinfo[threadIdx.x] = (q < base + cntr) ? p.idx[q] : INVALID_PAIR;
            }
            __syncthreads();

            // ======== mem gating + mem_tok GEMM + obs staging -> seqL ========
            {
                floatx4 accA[4][4] = {{z,z,z,z},{z,z,z,z},{z,z,z,z},{z,z,z,z}};
                floatx4 accB[4][4] = {{z,z,z,z},{z,z,z,z},{z,z,z,z},{z,z,z,z}};
                for (int kk = 0; kk < DIM; kk += 64){
                    __syncthreads();
                    {
                        int rr = threadIdx.x >> 2, s = threadIdx.x & 3;
                        unsigned short tmp[16];
                        #pragma unroll
                        for (int j = 0; j < 16; ++j) tmp[j] = 0;
                        if (rr < 32){
                            unsigned pi = pinfo[rr];
                            if (pi != INVALID_PAIR){
                                int tt = (int)(pi >> 8);
                                int b  = (int)(pi & 255u);
                                if (r == 0){
                                    int done = p.dones[pi];
                                    if (!done && tt == 0){
                                        const float* src = p.mem0 + (size_t)b * DIM + kk + s * 16;
                                        #pragma unroll
                                        for (int j = 0; j < 16; ++j) tmp[j] = f2b(src[j]);
                                    }
                                } else {
                                    const float* src = p.out + ((size_t)pi - NB) * DIM + kk + s * 16;
                                    #pragma unroll
                                    for (int j = 0; j < 16; ++j) tmp[j] = f2b(src[j]);
                                }
                            }
                        }
                        int4* dst = (int4*)(A_s + rr * 72 + s * 16);
                        dst[0] = *(int4*)tmp;
                        dst[1] = *(int4*)(tmp + 8);
                    }
                    __syncthreads();
                    mma44(A_s, 72, p.memkT + (size_t)(w*128 +  0) * DIM + kk, DIM, accA, lm, lq);
                    mma44(A_s, 72, p.memkT + (size_t)(w*128 + 64) * DIM + kk, DIM, accB, lm, lq);
                }
                __syncthreads();
                // write mem_tok rows (rows 0..31)
                #pragma unroll
                for (int am = 0; am < 2; ++am)
                #pragma unroll
                for (int an = 0; an < 4; ++an)
                #pragma unroll
                for (int i = 0; i < 4; ++i){
                    int row = am*16 + lq*4 + i;
                    seqL[row * SEQP + w*128 +      an*16 + lm] = accA[am][an][i];
                    seqL[row * SEQP + w*128 + 64 + an*16 + lm] = accB[am][an][i];
                }
                // obs rows (rows 32..63)
                {
                    int pp = threadIdx.x >> 3, seg = threadIdx.x & 7;
                    unsigned pi = pinfo[pp];
                    const float4 z4 = {0.f, 0.f, 0.f, 0.f};
                    if (pi != INVALID_PAIR){
                        const float* src = p.obs + (size_t)pi * DIM + seg * 64;
                        #pragma unroll
                        for (int j = 0; j < 64; j += 4)
                            *(float4*)&seqL[(32 + pp) * SEQP + seg*64 + j] = *(const float4*)(src + j);
                    } else {
                        #pragma unroll
                        for (int j = 0; j < 64; j += 4)
                            *(float4*)&seqL[(32 + pp) * SEQP + seg*64 + j] = z4;
                    }
                }
                __syncthreads();
            }

            // ======== 4 transformer layers, fully block-local ========
            for (int l = 0; l < NLAY; ++l){
                const unsigned short* wqkv = p.qkvT + (size_t)l * 786432;
                const unsigned short* wol  = p.woT  + (size_t)l * 262144;
                const unsigned short* w1l  = p.w1T  + (size_t)l * 1048576;
                const unsigned short* w2l  = p.w2T  + (size_t)l * 1048576;

                // ---- P1: LN1 + per-head QKV + attention + O-proj ----
                ln_statsL(seqL, redQ, mu_s, rs_s);
                floatx4 aoA[4][4] = {{z,z,z,z},{z,z,z,z},{z,z,z,z},{z,z,z,z}};
                floatx4 aoB[4][4] = {{z,z,z,z},{z,z,z,z},{z,z,z,z},{z,z,z,z}};
                for (int h = 0; h < 8; ++h){
                    floatx4 acc3[3][2][2] = {{{z,z},{z,z}},{{z,z},{z,z}},{{z,z},{z,z}}};
                    for (int kk = 0; kk < DIM; kk += 64){
                        __syncthreads();
                        stageA_lnL(seqL, kk, p.ln1s + l*DIM, p.ln1b + l*DIM, mu_s, rs_s, A_s);
                        __syncthreads();
                        #pragma unroll
                        for (int sec = 0; sec < 3; ++sec)
                            mma_g(A_s, 72, wqkv + (size_t)(sec*512 + h*64) * DIM + kk, DIM,
                                  acc3[sec], wm, wn, lm, lq);
                    }
                    __syncthreads();   // A_s free -> holds V now
                    {
                        const float* bql = p.bq + l*DIM + h*64;
                        const float* bkl = p.bk + l*DIM + h*64;
                        const float* bvl = p.bv + l*DIM + h*64;
                        #pragma unroll
                        for (int sec = 0; sec < 3; ++sec){
                            unsigned short* dstT = (sec == 0) ? Q_s : ((sec == 1) ? K_s : A_s);
                            const float* bias = (sec == 0) ? bql : ((sec == 1) ? bkl : bvl);
                            #pragma unroll
                            for (int fm = 0; fm < 2; ++fm)
                            #pragma unroll
                            for (int fn = 0; fn < 2; ++fn)
                            #pragma unroll
                            for (int i = 0; i < 4; ++i){
                                int row = wm*32 + fm*16 + lq*4 + i;
                                int col = wn*32 + fn*16 + lm;
                                dstT[row*72 + col] = f2b(acc3[sec][fm][fn][i] + bias[col]);
                            }
                        }
                    }
                    __syncthreads();
                    // scores + 2-token softmax (row i pairs with rows (i&31), 32+(i&31))
                    if (threadIdx.x < 64){
                        int i = threadIdx.x, pr = i & 31;
                        const unsigned short* qrow = Q_s + i*72;
                        const unsigned short* k0 = K_s + pr*72;
                        const unsigned short* k1 = K_s + (32 + pr)*72;
                        float s0 = 0.f, s1 = 0.f;
                        #pragma unroll
                        for (int d8 = 0; d8 < 8; ++d8){
                            short8 qa = *(const short8*)(qrow + d8*8);
                            short8 ka = *(const short8*)(k0 + d8*8);
                            short8 kb = *(const short8*)(k1 + d8*8);
                            #pragma unroll
                            for (int j = 0; j < 8; ++j){
                                float q = b2f((unsigned short)qa[j]);
                                s0 += q * b2f((unsigned short)ka[j]);
                                s1 += q * b2f((unsigned short)kb[j]);
                            }
                        }
                        s0 *= 0.125f; s1 *= 0.125f;
                        float mx = fmaxf(s0, s1);
                        float e0 = __expf(s0 - mx), e1 = __expf(s1 - mx);
                        float inv = 1.f / (e0 + e1);
                        p_lds[i*2 + 0] = e0 * inv;
                        p_lds[i*2 + 1] = e1 * inv;
                    }
                    __syncthreads();
                    // O = P @ V  (V in A_s) -> write O tile into Q_s
                    {
                        int i2 = threadIdx.x >> 2, seg = threadIdx.x & 3;
                        float p0 = p_lds[i2*2 + 0], p1 = p_lds[i2*2 + 1];
                        const unsigned short* v0 = A_s + (i2 & 31)*72 + seg*16;
                        const unsigned short* v1 = A_s + (32 + (i2 & 31))*72 + seg*16;
                        unsigned short o[16];
                        #pragma unroll
                        for (int j = 0; j < 16; ++j)
                            o[j] = f2b(p0 * b2f(v0[j]) + p1 * b2f(v1[j]));
                        int4* dst = (int4*)(Q_s + i2*72 + seg*16);
                        dst[0] = *(int4*)o;
                        dst[1] = *(int4*)(o + 8);
                    }
                    __syncthreads();
                    // O-proj partial (K = head h's 64 dims), accumulate in regs across heads
                    mma44(Q_s, 72, wol + (size_t)(w*128 +  0) * DIM + h*64, DIM, aoA, lm, lq);
                    mma44(Q_s, 72, wol + (size_t)(w*128 + 64) * DIM + h*64, DIM, aoB, lm, lq);
                }
                __syncthreads();
                // residual add: seq += O-proj (+bo)
                #pragma unroll
                for (int am = 0; am < 4; ++am)
                #pragma unroll
                for (int an = 0; an < 4; ++an)
                #pragma unroll
                for (int i = 0; i < 4; ++i){
                    int row = am*16 + lq*4 + i;
                    int cA = w*128 +      an*16 + lm;
                    int cB = w*128 + 64 + an*16 + lm;
                    seqL[row * SEQP + cA] += aoA[am][an][i] + p.bo[l*DIM + cA];
                    seqL[row * SEQP + cB] += aoB[am][an][i] + p.bo[l*DIM + cB];
                }
                __syncthreads();

                // ---- P2: LN2 + MLP (16 slices of 128 h1-cols) ----
                ln_statsL(seqL, (float*)h1_s, mu_s, rs_s);
                floatx4 a2A[4][4] = {{z,z,z,z},{z,z,z,z},{z,z,z,z},{z,z,z,z}};
                floatx4 a2B[4][4] = {{z,z,z,z},{z,z,z,z},{z,z,z,z},{z,z,z,z}};
                for (int sl = 0; sl < 16; ++sl){
                    int c0 = sl * 128;
                    floatx4 m1[4][2] = {{z,z},{z,z},{z,z},{z,z}};
                    for (int kk = 0; kk < DIM; kk += 64){
                        __syncthreads();
                        stageA_lnL(seqL, kk, p.ln2s + l*DIM, p.ln2b + l*DIM, mu_s, rs_s, A_s);
                        __syncthreads();
                        mma42(A_s, 72, w1l + (size_t)(c0 + w*32) * DIM + kk, DIM, m1, lm, lq);
                    }
                    __syncthreads();
                    // bias + gelu -> h1 slice
                    {
                        const float* b1l = p.b1 + l*MLPD + c0;
                        #pragma unroll
                        for (int am = 0; am < 4; ++am)
                        #pragma unroll
                        for (int an = 0; an < 2; ++an)
                        #pragma unroll
                        for (int i = 0; i < 4; ++i){
                            int row = am*16 + lq*4 + i;
                            int col = w*32 + an*16 + lm;
                            float v = m1[am][an][i] + b1l[col];
                            float g = 0.5f * v * (1.f + tanhf(0.7978845608028654f * (v + 0.044715f * v * v * v)));
                            h1_s[row*136 + col] = f2b(g);
                        }
                    }
                    __syncthreads();
                    // MLP2 partial over this slice's K=128
                    #pragma unroll
                    for (int c = 0; c < 2; ++c){
                        mma44(h1_s + c*64, 136, w2l + (size_t)(w*128 +  0) * MLPD + c0 + c*64, MLPD, a2A, lm, lq);
                        mma44(h1_s + c*64, 136, w2l + (size_t)(w*128 + 64) * MLPD + c0 + c*64, MLPD, a2B, lm, lq);
                    }
                }
                __syncthreads();
                // residual add: seq += MLP2 (+b2)
                #pragma unroll
                for (int am = 0; am < 4; ++am)
                #pragma unroll
                for (int an = 0; an < 4; ++an)
                #pragma unroll
                for (int i = 0; i < 4; ++i){
                    int row = am*16 + lq*4 + i;
                    int cA = w*128 +      an*16 + lm;
                    int cB = w*128 + 64 + an*16 + lm;
                    seqL[row * SEQP + cA] += a2A[am][an][i] + p.b2[l*DIM + cA];
                    seqL[row * SEQP + cB] += a2B[am][an][i] + p.b2[l*DIM + cB];
                }
                __syncthreads();
            }

            // ======== write out[t,b] = seq row 32+p ========
            {
                int pp = threadIdx.x >> 3, seg = threadIdx.x & 7;
                unsigned pi = pinfo[pp];
                if (pi != INVALID_PAIR){
                    float* o = p.out + (size_t)pi * DIM + seg * 64;
                    #pragma unroll
                    for (int j = 0; j < 64; j += 4)
                        *(float4*)(o + j) = *(const float4*)&seqL[(32 + pp) * SEQP + seg*64 + j];
                }
            }
            __syncthreads();
        }
        ++gen; gbar(p.bar, gen);
    }
}

// ---------------- fallback per-phase kernels (used only if cooperative launch fails) ----------------
static __device__ __forceinline__ void stage64(const unsigned short* __restrict__ g,
        int rstride, unsigned short* lds){
    int r = threadIdx.x >> 2, s = threadIdx.x & 3;
    const int4* src = (const int4*)(g + (size_t)r * rstride + s * 16);
    int4* dst = (int4*)(lds + r * 72 + s * 16);
    dst[0] = src[0];
    dst[1] = src[1];
}

static __device__ __forceinline__ void mma_chunk(const unsigned short* __restrict__ A_s, int astride,
        const unsigned short* __restrict__ B_s, floatx4 acc[2][2], int wm, int wn, int lm, int lq){
    #pragma unroll
    for (int ks = 0; ks < 2; ++ks){
        short8 a0 = *(const short8*)(A_s + (wm*32 + lm) * astride + ks*32 + lq*8);
        short8 a1 = *(const short8*)(A_s + (wm*32 + 16 + lm) * astride + ks*32 + lq*8);
        short8 b0 = *(const short8*)(B_s + (wn*32 + lm) * 72 + ks*32 + lq*8);
        short8 b1 = *(const short8*)(B_s + (wn*32 + 16 + lm) * 72 + ks*32 + lq*8);
        acc[0][0] = __builtin_amdgcn_mfma_f32_16x16x32_bf16(a0, b0, acc[0][0], 0, 0, 0);
        acc[0][1] = __builtin_amdgcn_mfma_f32_16x16x32_bf16(a0, b1, acc[0][1], 0, 0, 0);
        acc[1][0] = __builtin_amdgcn_mfma_f32_16x16x32_bf16(a1, b0, acc[1][0], 0, 0, 0);
        acc[1][1] = __builtin_amdgcn_mfma_f32_16x16x32_bf16(a1, b1, acc[1][1], 0, 0, 0);
    }
}

static __device__ __forceinline__ void ln_stats(const float* __restrict__ seq, int row0,
        float* mu_s, float* rs_s, float* red){
    int r = threadIdx.x >> 2, p = threadIdx.x & 3;
    const float* s = seq + (size_t)(row0 + r) * DIM + p * 128;
    float sm = 0.f, ss = 0.f;
    for (int k = 0; k < 128; k += 4){
        float4 v = *(const float4*)(s + k);
        sm += v.x + v.y + v.z + v.w;
        ss += v.x*v.x + v.y*v.y + v.z*v.z + v.w*v.w;
    }
    red[r*8 + p] = sm;
    red[r*8 + 4 + p] = ss;
    __syncthreads();
    if (threadIdx.x < 64){
        int rr = threadIdx.x;
        float s4 = red[rr*8+0] + red[rr*8+1] + red[rr*8+2] + red[rr*8+3];
        float q4 = red[rr*8+4] + red[rr*8+5] + red[rr*8+6] + red[rr*8+7];
        float mu = s4 * (1.f / DIM);
        float var = q4 * (1.f / DIM) - mu * mu;
        mu_s[rr] = mu;
        rs_s[rr] = rsqrtf(var + 1e-6f);
    }
    __syncthreads();
}

static __device__ __forceinline__ void stageA_ln(const float* __restrict__ seq, int row0, int kk,
        const float* __restrict__ lns, const float* __restrict__ lnb,
        const float* mu_s, const float* rs_s, unsigned short* lds){
    int r = threadIdx.x >> 2, s = threadIdx.x & 3;
    const float* src = seq + (size_t)(row0 + r) * DIM + kk + s * 16;
    float mu = mu_s[r], rs = rs_s[r];
    unsigned short tmp[16];
    #pragma unroll
    for (int j = 0; j < 16; ++j){
        float g = lns[kk + s*16 + j];
        float bb = lnb[kk + s*16 + j];
        tmp[j] = f2b((src[j] - mu) * rs * g + bb);
    }
    int4* dst = (int4*)(lds + r * 72 + s * 16);
    dst[0] = *(int4*)(tmp);
    dst[1] = *(int4*)(tmp + 8);
}

__global__ __launch_bounds__(256) void k_memgemm(int t,
        const float* __restrict__ obs, const int* __restrict__ dones,
        const float* __restrict__ mem0, const float* __restrict__ seqprev,
        const unsigned short* __restrict__ wT, float* __restrict__ seqcur,
        float* __restrict__ outprev){
    __shared__ unsigned short A_s[64*72];
    __shared__ unsigned short B_s[64*72];
    int n0 = blockIdx.x * 64, m0 = blockIdx.y * 64;
    int wave = threadIdx.x >> 6, lane = threadIdx.x & 63;
    int wm = wave >> 1, wn = wave & 1, lm = lane & 15, lq = lane >> 4;
    floatx4 z = {0.f, 0.f, 0.f, 0.f};
    floatx4 acc[2][2] = {{z, z}, {z, z}};
    for (int kk = 0; kk < DIM; kk += 64){
        __syncthreads();
        {
            int r = threadIdx.x >> 2, s = threadIdx.x & 3;
            int b = m0 + r;
            int done = dones[b];
            unsigned short tmp[16];
            if (t == 0){
                const float* src = mem0 + (size_t)b * DIM + kk + s * 16;
                #pragma unroll
                for (int j = 0; j < 16; ++j) tmp[j] = done ? (unsigned short)0 : f2b(src[j]);
            } else {
                const float* src = seqprev + (size_t)(2*b + 1) * DIM + kk + s * 16;
                #pragma unroll
                for (int j = 0; j < 16; ++j){
                    float x = src[j];
                    if (blockIdx.x == 0) outprev[(size_t)b * DIM + kk + s*16 + j] = x;
                    tmp[j] = done ? (unsigned short)0 : f2b(x);
                }
            }
            int4* dst = (int4*)(A_s + r * 72 + s * 16);
            dst[0] = *(int4*)tmp;
            dst[1] = *(int4*)(tmp + 8);
        }
        stage64(wT + (size_t)n0 * DIM + kk, DIM, B_s);
        __syncthreads();
        mma_chunk(A_s, 72, B_s, acc, wm, wn, lm, lq);
    }
    #pragma unroll
    for (int fm = 0; fm < 2; ++fm)
    #pragma unroll
    for (int fn = 0; fn < 2; ++fn)
    #pragma unroll
    for (int i = 0; i < 4; ++i){
        int b = m0 + wm*32 + fm*16 + lq*4 + i;
        int c = n0 + wn*32 + fn*16 + lm;
        seqcur[(size_t)(2*b) * DIM + c] = acc[fm][fn][i];
        seqcur[(size_t)(2*b + 1) * DIM + c] = obs[(size_t)b * DIM + c];
    }
}

__global__ __launch_bounds__(256) void k_qkv(const float* __restrict__ seq,
        const unsigned short* __restrict__ wT,
        const float* __restrict__ bq, const float* __restrict__ bk,
        const float* __restrict__ bv,
        const float* __restrict__ lns, const float* __restrict__ lnb,
        unsigned short* __restrict__ qkv){
    __shared__ unsigned short A_s[64*72];
    __shared__ unsigned short B_s[64*72];
    __shared__ float red[64*8];
    __shared__ float mu_s[64], rs_s[64];
    int n0 = blockIdx.x * 64, m0 = blockIdx.y * 64;
    ln_stats(seq, m0, mu_s, rs_s, red);
    int wave = threadIdx.x >> 6, lane = threadIdx.x & 63;
    int wm = wave >> 1, wn = wave & 1, lm = lane & 15, lq = lane >> 4;
    floatx4 z = {0.f, 0.f, 0.f, 0.f};
    floatx4 acc[2][2] = {{z, z}, {z, z}};
    for (int kk = 0; kk < DIM; kk += 64){
        __syncthreads();
        stageA_ln(seq, m0, kk, lns, lnb, mu_s, rs_s, A_s);
        stage64(wT + (size_t)n0 * DIM + kk, DIM, B_s);
        __syncthreads();
        mma_chunk(A_s, 72, B_s, acc, wm, wn, lm, lq);
    }
    int sec = n0 >> 9;
    const float* bias = (sec == 0) ? bq : ((sec == 1) ? bk : bv);
    int nsec = n0 & 511;
    #pragma unroll
    for (int fm = 0; fm < 2; ++fm)
    #pragma unroll
    for (int fn = 0; fn < 2; ++fn)
    #pragma unroll
    for (int i = 0; i < 4; ++i){
        int row = m0 + wm*32 + fm*16 + lq*4 + i;
        int cl = wn*32 + fn*16 + lm;
        float v = acc[fm][fn][i] + bias[nsec + cl];
        qkv[(size_t)row * QKVW + n0 + cl] = f2b(v);
    }
}

__global__ __launch_bounds__(256) void k_attno(const unsigned short* __restrict__ qkv,
        const unsigned short* __restrict__ wT,
        const float* __restrict__ bo, float* __restrict__ seq){
    __shared__ unsigned short O_s[64*264];
    __shared__ unsigned short B_s[64*72];
    int n0 = blockIdx.x * 64, m0 = blockIdx.y * 64;
    int sp = blockIdx.z;
    if (threadIdx.x < 128){
        int b_l = threadIdx.x >> 2, h_l = threadIdx.x & 3;
        int h = sp * 4 + h_l;
        const unsigned short* q0 = qkv + (size_t)(m0 + 2*b_l) * QKVW + h * 64;
        const unsigned short* q1 = q0 + QKVW;
        const unsigned short* k0p = q0 + 512;
        const unsigned short* k1p = k0p + QKVW;
        const unsigned short* v0p = q0 + 1024;
        const unsigned short* v1p = v0p + QKVW;
        float s00 = 0, s01 = 0, s10 = 0, s11 = 0;
        for (int f8 = 0; f8 < 8; ++f8){
            short8 a0 = *(const short8*)(q0 + f8*8);
            short8 a1 = *(const short8*)(q1 + f8*8);
            short8 c0 = *(const short8*)(k0p + f8*8);
            short8 c1 = *(const short8*)(k1p + f8*8);
            #pragma unroll
            for (int j = 0; j < 8; ++j){
                float qa = b2f((unsigned short)a0[j]);
                float qb = b2f((unsigned short)a1[j]);
                float ka = b2f((unsigned short)c0[j]);
                float kb = b2f((unsigned short)c1[j]);
                s00 += qa*ka; s01 += qa*kb; s10 += qb*ka; s11 += qb*kb;
            }
        }
        s00 *= 0.125f; s01 *= 0.125f; s10 *= 0.125f; s11 *= 0.125f;
        float m0v = fmaxf(s00, s01), m1v = fmaxf(s10, s11);
        float e00 = __expf(s00 - m0v), e01 = __expf(s01 - m0v);
        float e10 = __expf(s10 - m1v), e11 = __expf(s11 - m1v);
        float i0 = 1.f / (e00 + e01), i1 = 1.f / (e10 + e11);
        float p00 = e00*i0, p01 = e01*i0, p10 = e10*i1, p11 = e11*i1;
        for (int f8 = 0; f8 < 8; ++f8){
            short8 va = *(const short8*)(v0p + f8*8);
            short8 vb = *(const short8*)(v1p + f8*8);
            unsigned short o0[8], o1[8];
            #pragma unroll
            for (int j = 0; j < 8; ++j){
                float x0 = b2f((unsigned short)va[j]);
                float x1 = b2f((unsigned short)vb[j]);
                o0[j] = f2b(p00*x0 + p01*x1);
                o1[j] = f2b(p10*x0 + p11*x1);
            }
            *(int4*)(O_s + (2*b_l) * 264 + h_l*64 + f8*8) = *(int4*)o0;
            *(int4*)(O_s + (2*b_l + 1) * 264 + h_l*64 + f8*8) = *(int4*)o1;
        }
    }
    int wave = threadIdx.x >> 6, lane = threadIdx.x & 63;
    int wm = wave >> 1, wn = wave & 1, lm = lane & 15, lq = lane >> 4;
    floatx4 z = {0.f, 0.f, 0.f, 0.f};
    floatx4 acc[2][2] = {{z, z}, {z, z}};
    for (int c = 0; c < 4; ++c){
        int kkg = sp * 256 + c * 64;
        __syncthreads();
        stage64(wT + (size_t)n0 * DIM + kkg, DIM, B_s);
        __syncthreads();
        mma_chunk(O_s + c * 64, 264, B_s, acc, wm, wn, lm, lq);
    }
    #pragma unroll
    for (int fm = 0; fm < 2; ++fm)
    #pragma unroll
    for (int fn = 0; fn < 2; ++fn)
    #pragma unroll
    for (int i = 0; i < 4; ++i){
        int row = m0 + wm*32 + fm*16 + lq*4 + i;
        int cc = n0 + wn*32 + fn*16 + lm;
        float v = acc[fm][fn][i];
        if (sp == 0) v += bo[cc];
        atomicAdd(&seq[(size_t)row * DIM + cc], v);
    }
}

__global__ __launch_bounds__(256) void k_mlp1(const float* __restrict__ seq,
        const unsigned short* __restrict__ wT, const float* __restrict__ b1,
        const float* __restrict__ lns, const float* __restrict__ lnb,
        unsigned short* __restrict__ h1){
    __shared__ unsigned short A_s[64*72];
    __shared__ unsigned short B_s[64*72];
    __shared__ float red[64*8];
    __shared__ float mu_s[64], rs_s[64];
    int n0 = blockIdx.x * 64, m0 = blockIdx.y * 64;
    ln_stats(seq, m0, mu_s, rs_s, red);
    int wave = threadIdx.x >> 6, lane = threadIdx.x & 63;
    int wm = wave >> 1, wn = wave & 1, lm = lane & 15, lq = lane >> 4;
    floatx4 z = {0.f, 0.f, 0.f, 0.f};
    floatx4 acc[2][2] = {{z, z}, {z, z}};
    for (int kk = 0; kk < DIM; kk += 64){
        __syncthreads();
        stageA_ln(seq, m0, kk, lns, lnb, mu_s, rs_s, A_s);
        stage64(wT + (size_t)n0 * DIM + kk, DIM, B_s);
        __syncthreads();
        mma_chunk(A_s, 72, B_s, acc, wm, wn, lm, lq);
    }
    #pragma unroll
    for (int fm = 0; fm < 2; ++fm)
    #pragma unroll
    for (int fn = 0; fn < 2; ++fn)
    #pragma unroll
    for (int i = 0; i < 4; ++i){
        int row = m0 + wm*32 + fm*16 + lq*4 + i;
        int cc = n0 + wn*32 + fn*16 + lm;
        float v = acc[fm][fn][i] + b1[cc];
        float g = 0.5f * v * (1.f + tanhf(0.7978845608028654f * (v + 0.044715f * v * v * v)));
        h1[(size_t)row * MLPD + cc] = f2b(g);
    }
}

__global__ __launch_bounds__(256) void k_mlp2(const unsigned short* __restrict__ h1,
        const unsigned short* __restrict__ wT, const float* __restrict__ b2,
        float* __restrict__ seq){
    __shared__ unsigned short A_s[64*72];
    __shared__ unsigned short B_s[64*72];
    int n0 = blockIdx.x * 64, m0 = blockIdx.y * 64;
    int sp = blockIdx.z;
    int wave = threadIdx.x >> 6, lane = threadIdx.x & 63;
    int wm = wave >> 1, wn = wave & 1, lm = lane & 15, lq = lane >> 4;
    floatx4 z = {0.f, 0.f, 0.f, 0.f};
    floatx4 acc[2][2] = {{z, z}, {z, z}};
    for (int c = 0; c < 8; ++c){
        int kk = sp * 512 + c * 64;
        __syncthreads();
        stage64(h1 + (size_t)m0 * MLPD + kk, MLPD, A_s);
        stage64(wT + (size_t)n0 * MLPD + kk, MLPD, B_s);
        __syncthreads();
        mma_chunk(A_s, 72, B_s, acc, wm, wn, lm, lq);
    }
    #pragma unroll
    for (int fm = 0; fm < 2; ++fm)
    #pragma unroll
    for (int fn = 0; fn < 2; ++fn)
    #pragma unroll
    for (int i = 0; i < 4; ++i){
        int row = m0 + wm*32 + fm*16 + lq*4 + i;
        int cc = n0 + wn*32 + fn*16 + lm;
        float v = acc[fm][fn][i];
        if (sp == 0) v += b2[cc];
        atomicAdd(&seq[(size_t)row * DIM + cc], v);
    }
}

__global__ __launch_bounds__(256) void k_flush(const float* __restrict__ seq,
        float* __restrict__ out){
    int idx = blockIdx.x * 256 + threadIdx.x;
    int b = idx >> 9, c = idx & 511;
    out[idx] = seq[(size_t)(2*b + 1) * DIM + c];
}

// ---------------- host launch ----------------
extern "C" void kernel_launch(void* const* d_in, const int* in_sizes, int n_in,
                              void* d_out, int out_size, void* d_ws, size_t ws_size,
                              hipStream_t stream){
    const float* obs  = (const float*)d_in[0];
    const int*   dones= (const int*)d_in[1];
    const float* mem0 = (const float*)d_in[2];
    const float* memk = (const float*)d_in[3];
    const float* ln1s = (const float*)d_in[4];
    const float* ln1b = (const float*)d_in[5];
    const float* wq   = (const float*)d_in[6];
    const float* bq   = (const float*)d_in[7];
    const float* wk   = (const float*)d_in[8];
    const float* bk   = (const float*)d_in[9];
    const float* wv   = (const float*)d_in[10];
    const float* bv   = (const float*)d_in[11];
    const float* wo   = (const float*)d_in[12];
    const float* bo   = (const float*)d_in[13];
    const float* ln2s = (const float*)d_in[14];
    const float* ln2b = (const float*)d_in[15];
    const float* w1   = (const float*)d_in[16];
    const float* b1   = (const float*)d_in[17];
    const float* w2   = (const float*)d_in[18];
    const float* b2   = (const float*)d_in[19];
    float* out = (float*)d_out;

    char* ws = (char*)d_ws;
    unsigned short* memkT = (unsigned short*)(ws + 0);          // 512*512 bf16
    unsigned short* qkvT  = (unsigned short*)(ws + 524288);     // 4*1536*512
    unsigned short* woT   = (unsigned short*)(ws + 6815744);    // 4*512*512
    unsigned short* w1T   = (unsigned short*)(ws + 8912896);    // 4*2048*512
    unsigned short* w2T   = (unsigned short*)(ws + 17301504);   // 4*512*2048
    // persistent-path arrays (alias the fallback seq0 region; mutually exclusive)
    unsigned* idxg        = (unsigned*)(ws + 25690112);         // 65536 u32
    unsigned* offg        = (unsigned*)(ws + 25952256);         // 258 u32 (pad 2KB)
    unsigned* bar         = (unsigned*)(ws + 25954304);         // 32 u32
    // fallback-path buffers (old layout)
    float* seq0           = (float*)(ws + 25690112);
    float* seq1           = (float*)(ws + 26738688);
    unsigned short* qkv   = (unsigned short*)(ws + 27787264);
    unsigned short* h1    = (unsigned short*)(ws + 29360128);

    dim3 blk(256);
    k_transpose<<<dim3(8, 8), blk, 0, stream>>>(memk, memkT, 512, 512);
    for (int l = 0; l < NLAY; ++l){
        k_transpose<<<dim3(8, 8), blk, 0, stream>>>(wq + (size_t)l*262144, qkvT + (size_t)l*786432,          512, 512);
        k_transpose<<<dim3(8, 8), blk, 0, stream>>>(wk + (size_t)l*262144, qkvT + (size_t)l*786432 + 262144, 512, 512);
        k_transpose<<<dim3(8, 8), blk, 0, stream>>>(wv + (size_t)l*262144, qkvT + (size_t)l*786432 + 524288, 512, 512);
        k_transpose<<<dim3(8, 8), blk, 0, stream>>>(wo + (size_t)l*262144, woT + (size_t)l*262144,           512, 512);
        k_transpose<<<dim3(8, 32), blk, 0, stream>>>(w1 + (size_t)l*1048576, w1T + (size_t)l*1048576,        512, 2048);
        k_transpose<<<dim3(32, 8), blk, 0, stream>>>(w2 + (size_t)l*1048576, w2T + (size_t)l*1048576,        2048, 512);
    }
    k_depth<<<dim3(1), blk, 0, stream>>>(dones, offg, idxg);
    k_zero<<<dim3(1), blk, 0, stream>>>(bar);

    P prm;
    prm.obs = obs; prm.dones = dones; prm.mem0 = mem0;
    prm.memkT = memkT; prm.qkvT = qkvT; prm.woT = woT; prm.w1T = w1T; prm.w2T = w2T;
    prm.ln1s = ln1s; prm.ln1b = ln1b; prm.bq = bq; prm.bk = bk; prm.bv = bv;
    prm.bo = bo; prm.ln2s = ln2s; prm.ln2b = ln2b; prm.b1 = b1; prm.b2 = b2;
    prm.off = offg; prm.idx = idxg; prm.out = out; prm.bar = bar;

    hipError_t ce = hipFuncSetAttribute((const void*)k_persist,
            hipFuncAttributeMaxDynamicSharedMemorySize, 160384);
    if (ce == hipSuccess){
        void* kargs[] = { (void*)&prm };
        ce = hipLaunchCooperativeKernel((const void*)k_persist,
                dim3(GRID), dim3(256), kargs, 160384, stream);
    }

    if (ce != hipSuccess){
        // fallback: per-phase launch sequence (proven path)
        for (int t = 0; t < NT; ++t){
            float* scur  = (t & 1) ? seq1 : seq0;
            float* sprev = (t & 1) ? seq0 : seq1;
            k_memgemm<<<dim3(8, 4), blk, 0, stream>>>(t,
                    obs + (size_t)t * NB * DIM, dones + t * NB, mem0,
                    sprev, memkT, scur,
                    out + (size_t)(t > 0 ? t - 1 : 0) * NB * DIM);
            for (int l = 0; l < NLAY; ++l){
                k_qkv<<<dim3(24, 8), blk, 0, stream>>>(scur, qkvT + (size_t)l*786432,
                        bq + l*512, bk + l*512, bv + l*512, ln1s + l*512, ln1b + l*512, qkv);
                k_attno<<<dim3(8, 8, 2), blk, 0, stream>>>(qkv, woT + (size_t)l*262144, bo + l*512, scur);
                k_mlp1<<<dim3(32, 8, 1), blk, 0, stream>>>(scur, w1T + (size_t)l*1048576, b1 + l*2048,
                        ln2s + l*512, ln2b + l*512, h1);
                k_mlp2<<<dim3(8, 8, 4), blk, 0, stream>>>(h1, w2T + (size_t)l*1048576, b2 + l*512, scur);
            }
        }
        k_flush<<<dim3(512), blk, 0, stream>>>(((NT - 1) & 1) ? seq1 : seq0,
                out + (size_t)(NT - 1) * NB * DIM);
    }
}

// Round 4
// 18458.228 us; speedup vs baseline: 16.2830x; 2.3010x over previous
//
#include <hip/hip_runtime.h>

#define DIM   512
#define QKVW  1536
#define MLPD  2048
#define NB    256
#define NT    256
#define NLAY  4
#define GRID  256
#define INVALID_PAIR 0xFFFFFFFFu

typedef __attribute__((ext_vector_type(8))) short short8;
typedef __attribute__((ext_vector_type(4))) float floatx4;

static __device__ __forceinline__ float b2f(unsigned short x){
    return __uint_as_float(((unsigned int)x) << 16);
}
static __device__ __forceinline__ unsigned short f2b(float f){
    unsigned int u = __float_as_uint(f);
    u += 0x7fffu + ((u >> 16) & 1u);
    return (unsigned short)(u >> 16);
}

// ---------------- one-time weight transpose+cast: src f32[K][N] -> dst bf16[N][K] ----------------
__global__ __launch_bounds__(256) void k_transpose(const float* __restrict__ src,
        unsigned short* __restrict__ dst, int K, int N){
    __shared__ unsigned short tile[64][65];
    int r0 = blockIdx.x * 64, c0 = blockIdx.y * 64;
    int tx = threadIdx.x & 63, ty = threadIdx.x >> 6;
    #pragma unroll
    for (int i = 0; i < 16; ++i){
        int r = ty + 4 * i;
        tile[r][tx] = f2b(src[(size_t)(r0 + r) * N + c0 + tx]);
    }
    __syncthreads();
    #pragma unroll
    for (int i = 0; i < 16; ++i){
        int r = ty + 4 * i;
        dst[(size_t)(c0 + r) * K + r0 + tx] = tile[tx][r];
    }
}

// ---------------- depth/round index precompute (single block) ----------------
__global__ __launch_bounds__(256) void k_depth(const int* __restrict__ dones,
        unsigned* __restrict__ offg, unsigned* __restrict__ idxg){
    __shared__ unsigned cnt[256];
    __shared__ unsigned pos[256];
    int b = threadIdx.x;
    cnt[b] = 0;
    __syncthreads();
    unsigned d = 0;
    for (int t = 0; t < NT; ++t){
        int done = dones[t * NB + b];
        d = (t == 0) ? 0u : (done ? 0u : d + 1u);
        atomicAdd(&cnt[d], 1u);
    }
    __syncthreads();
    if (b == 0){
        unsigned s = 0, mx = 0;
        for (int r = 0; r < 256; ++r){
            pos[r] = s;
            offg[r] = s;
            if (cnt[r]) mx = (unsigned)r;
            s += cnt[r];
        }
        offg[256] = s;
        offg[257] = mx + 1;   // number of rounds
    }
    __syncthreads();
    d = 0;
    for (int t = 0; t < NT; ++t){
        int done = dones[t * NB + b];
        d = (t == 0) ? 0u : (done ? 0u : d + 1u);
        unsigned q = atomicAdd(&pos[d], 1u);
        idxg[q] = (unsigned)(t * NB + b);
    }
}

__global__ __launch_bounds__(256) void k_zero(unsigned* p){
    if (threadIdx.x < 32) p[threadIdx.x] = 0;
}

// ---------------- grid barrier (monotonic generation, agent scope) ----------------
static __device__ __forceinline__ void gbar(unsigned* bar, unsigned gen){
    __syncthreads();
    if (threadIdx.x == 0){
        __builtin_amdgcn_fence(__ATOMIC_RELEASE, "agent");
        unsigned arrived = __hip_atomic_fetch_add(&bar[0], 1u,
                __ATOMIC_RELAXED, __HIP_MEMORY_SCOPE_AGENT) + 1u;
        if (arrived == (unsigned)GRID * gen){
            __hip_atomic_store(&bar[16], gen, __ATOMIC_RELAXED, __HIP_MEMORY_SCOPE_AGENT);
        } else {
            while (__hip_atomic_load(&bar[16], __ATOMIC_RELAXED, __HIP_MEMORY_SCOPE_AGENT) < gen)
                __builtin_amdgcn_s_sleep(32);
        }
        __builtin_amdgcn_fence(__ATOMIC_ACQUIRE, "agent");
    }
    __syncthreads();
}

// ---------------- MFMA helpers ----------------
// one wave: 64 rows x 64 cols over K=64; A from LDS (stride astride shorts), B [N][K] (global or LDS)
static __device__ __forceinline__ void mma44(const unsigned short* __restrict__ A_s, int astride,
        const unsigned short* __restrict__ Bg, int bstride, floatx4 acc[4][4], int lm, int lq){
    #pragma unroll
    for (int ks = 0; ks < 2; ++ks){
        short8 a[4], b[4];
        #pragma unroll
        for (int m = 0; m < 4; ++m)
            a[m] = *(const short8*)(A_s + (m*16 + lm) * astride + ks*32 + lq*8);
        #pragma unroll
        for (int n = 0; n < 4; ++n)
            b[n] = *(const short8*)(Bg + (size_t)(n*16 + lm) * bstride + ks*32 + lq*8);
        #pragma unroll
        for (int m = 0; m < 4; ++m)
        #pragma unroll
        for (int n = 0; n < 4; ++n)
            acc[m][n] = __builtin_amdgcn_mfma_f32_16x16x32_bf16(a[m], b[n], acc[m][n], 0, 0, 0);
    }
}

// one wave: 64 rows x 32 cols over K=64
static __device__ __forceinline__ void mma42(const unsigned short* __restrict__ A_s, int astride,
        const unsigned short* __restrict__ Bg, int bstride, floatx4 acc[4][2], int lm, int lq){
    #pragma unroll
    for (int ks = 0; ks < 2; ++ks){
        short8 a[4], b[2];
        #pragma unroll
        for (int m = 0; m < 4; ++m)
            a[m] = *(const short8*)(A_s + (m*16 + lm) * astride + ks*32 + lq*8);
        #pragma unroll
        for (int n = 0; n < 2; ++n)
            b[n] = *(const short8*)(Bg + (size_t)(n*16 + lm) * bstride + ks*32 + lq*8);
        #pragma unroll
        for (int m = 0; m < 4; ++m)
        #pragma unroll
        for (int n = 0; n < 2; ++n)
            acc[m][n] = __builtin_amdgcn_mfma_f32_16x16x32_bf16(a[m], b[n], acc[m][n], 0, 0, 0);
    }
}

// ---------------- persistent depth-parallel kernel ----------------
struct P {
    const float* obs; const int* dones; const float* mem0;
    const unsigned short* memkT;
    const unsigned short* qkvT; const unsigned short* woT;
    const unsigned short* w1T;  const unsigned short* w2T;
    const float *ln1s, *ln1b, *bq, *bk, *bv, *bo, *ln2s, *ln2b, *b1, *b2;
    const unsigned* off; const unsigned* idx;
    float* out;
    unsigned* bar;
};

// Residual stream lives in REGISTERS: wave w owns cols [w*64, w*64+64).
// sr[m][n][i]: row = m*16 + lq*4 + i (rows 0..31 = mem tokens, 32..63 = obs tokens),
//              col = w*64 + n*16 + lm.
//
// LDS layout (dynamic, 134784 B):
//   lnA   bf16 8 chunks x [64][72]   @ 0       (73728)  LN output, staged ONCE per LN
//   QKV_s bf16 [2][3][64][72]        @ 73728   (55296)  per head-pair Q/K/V (O reuses Q)
//   h1_s  bf16 [64][264]             @ 73728   (33792)  P2 slice (aliases QKV_s)
//   red   f32  [64][16]              @ 129024  (4096)
//   mu_s  f32  [64]                  @ 133120  (256)
//   rs_s  f32  [64]                  @ 133376  (256)
//   p_lds f32  [2][64][2]            @ 133632  (1024)
//   pinfo u32  [32]                  @ 134656  (128)

static __device__ __forceinline__ void ln_stats_reg(const floatx4 sr[4][4],
        float* red, float* mu_s, float* rs_s, int w, int lq, int lm){
    #pragma unroll
    for (int m = 0; m < 4; ++m)
    #pragma unroll
    for (int i = 0; i < 4; ++i){
        float s = sr[m][0][i] + sr[m][1][i] + sr[m][2][i] + sr[m][3][i];
        float q = sr[m][0][i]*sr[m][0][i] + sr[m][1][i]*sr[m][1][i]
                + sr[m][2][i]*sr[m][2][i] + sr[m][3][i]*sr[m][3][i];
        #pragma unroll
        for (int d = 1; d < 16; d <<= 1){
            s += __shfl_xor(s, d, 64);
            q += __shfl_xor(q, d, 64);
        }
        if (lm == 0){
            int row = m*16 + lq*4 + i;
            red[row*16 + w*2]     = s;
            red[row*16 + w*2 + 1] = q;
        }
    }
    __syncthreads();
    if (threadIdx.x < 64){
        int row = threadIdx.x;
        float s = 0.f, q = 0.f;
        #pragma unroll
        for (int ww = 0; ww < 8; ++ww){ s += red[row*16 + ww*2]; q += red[row*16 + ww*2 + 1]; }
        float mu = s * (1.f / DIM);
        float var = q * (1.f / DIM) - mu * mu;
        mu_s[row] = mu;
        rs_s[row] = rsqrtf(var + 1e-6f);
    }
    __syncthreads();
}

static __device__ __forceinline__ void stage_lnA_reg(const floatx4 sr[4][4],
        const float* __restrict__ lns, const float* __restrict__ lnb,
        const float* mu_s, const float* rs_s,
        unsigned short* lnA, int w, int lq, int lm){
    unsigned short* chunk = lnA + w * 4608;
    float g[4], bb[4];
    #pragma unroll
    for (int n = 0; n < 4; ++n){
        int gcol = w*64 + n*16 + lm;
        g[n] = lns[gcol]; bb[n] = lnb[gcol];
    }
    #pragma unroll
    for (int m = 0; m < 4; ++m)
    #pragma unroll
    for (int i = 0; i < 4; ++i){
        int row = m*16 + lq*4 + i;
        float mu = mu_s[row], rs = rs_s[row];
        #pragma unroll
        for (int n = 0; n < 4; ++n)
            chunk[row*72 + n*16 + lm] = f2b((sr[m][n][i] - mu) * rs * g[n] + bb[n]);
    }
}

__global__ __launch_bounds__(512, 1) void k_persist(P p){
    extern __shared__ __align__(16) char smem[];
    unsigned short* lnA   = (unsigned short*)smem;
    unsigned short* QKV_s = (unsigned short*)(smem + 73728);
    unsigned short* h1_s  = (unsigned short*)(smem + 73728);
    float*          red   = (float*)(smem + 129024);
    float*          mu_s  = (float*)(smem + 133120);
    float*          rs_s  = (float*)(smem + 133376);
    float*          p_lds = (float*)(smem + 133632);
    unsigned*       pinfo = (unsigned*)(smem + 134656);

    const int bid  = blockIdx.x;
    const int w    = threadIdx.x >> 6;       // wave 0..7
    const int lane = threadIdx.x & 63;
    const int lm = lane & 15, lq = lane >> 4;
    const floatx4 z = {0.f, 0.f, 0.f, 0.f};
    unsigned gen = 0;

    const int R = (int)p.off[257];

    for (int r = 0; r < R; ++r){
        unsigned base = p.off[r];
        unsigned cntr = p.off[r+1] - base;
        int tiles = (int)((cntr + 31u) >> 5);

        for (int tile = bid; tile < tiles; tile += GRID){
            __syncthreads();
            if (threadIdx.x < 32){
                unsigned q = base + (unsigned)tile * 32u + threadIdx.x;
                pinfo[threadIdx.x] = (q < base + cntr) ? p.idx[q] : INVALID_PAIR;
            }
            __syncthreads();

            floatx4 sr[4][4] = {{z,z,z,z},{z,z,z,z},{z,z,z,z},{z,z,z,z}};

            // ======== stage gated mem (rows 0..31) into lnA chunks; load obs -> sr[2..3] ========
            {
                int rr = threadIdx.x >> 4, half = threadIdx.x & 15;   // rr 0..31, 32 cols each
                int c = half >> 1, coff = (half & 1) * 32;
                unsigned pi = pinfo[rr];
                unsigned short tmp[32];
                #pragma unroll
                for (int j = 0; j < 32; ++j) tmp[j] = 0;
                if (pi != INVALID_PAIR){
                    if (r == 0){
                        int done = p.dones[pi];
                        int tt = (int)(pi >> 8);
                        if (!done && tt == 0){
                            const float* src = p.mem0 + (size_t)(pi & 255u) * DIM + c*64 + coff;
                            #pragma unroll
                            for (int j = 0; j < 32; ++j) tmp[j] = f2b(src[j]);
                        }
                    } else {
                        const float* src = p.out + ((size_t)pi - NB) * DIM + c*64 + coff;
                        #pragma unroll
                        for (int j = 0; j < 32; ++j) tmp[j] = f2b(src[j]);
                    }
                }
                int4* dst = (int4*)(lnA + c*4608 + rr*72 + coff);
                dst[0] = *(int4*)(tmp + 0);
                dst[1] = *(int4*)(tmp + 8);
                dst[2] = *(int4*)(tmp + 16);
                dst[3] = *(int4*)(tmp + 24);
            }
            // obs rows -> sr[2..3] (registers)
            #pragma unroll
            for (int m2 = 0; m2 < 2; ++m2)
            #pragma unroll
            for (int i = 0; i < 4; ++i){
                int pp = m2*16 + lq*4 + i;
                unsigned pi = pinfo[pp];
                #pragma unroll
                for (int n = 0; n < 4; ++n){
                    float v = 0.f;
                    if (pi != INVALID_PAIR)
                        v = p.obs[(size_t)pi * DIM + w*64 + n*16 + lm];
                    sr[2 + m2][n][i] = v;
                }
            }
            __syncthreads();

            // mem_tok GEMM: sr[0..1] += gatedmem @ memkT  (rows 0..31)
            for (int kk = 0; kk < 8; ++kk){
                const unsigned short* chunk = lnA + kk*4608;
                const unsigned short* Bg = p.memkT + (size_t)(w*64) * DIM + kk*64;
                #pragma unroll
                for (int ks = 0; ks < 2; ++ks){
                    short8 a0 = *(const short8*)(chunk + (lm) * 72 + ks*32 + lq*8);
                    short8 a1 = *(const short8*)(chunk + (16 + lm) * 72 + ks*32 + lq*8);
                    #pragma unroll
                    for (int n = 0; n < 4; ++n){
                        short8 b = *(const short8*)(Bg + (size_t)(n*16 + lm) * DIM + ks*32 + lq*8);
                        sr[0][n] = __builtin_amdgcn_mfma_f32_16x16x32_bf16(a0, b, sr[0][n], 0, 0, 0);
                        sr[1][n] = __builtin_amdgcn_mfma_f32_16x16x32_bf16(a1, b, sr[1][n], 0, 0, 0);
                    }
                }
            }

            // ======== 4 transformer layers, residual in registers ========
            for (int l = 0; l < NLAY; ++l){
                const unsigned short* wqkv = p.qkvT + (size_t)l * 786432;
                const unsigned short* wol  = p.woT  + (size_t)l * 262144;
                const unsigned short* w1l  = p.w1T  + (size_t)l * 1048576;
                const unsigned short* w2l  = p.w2T  + (size_t)l * 1048576;

                // ---- P1: LN1 -> lnA (once) ----
                ln_stats_reg(sr, red, mu_s, rs_s, w, lq, lm);
                stage_lnA_reg(sr, p.ln1s + l*DIM, p.ln1b + l*DIM, mu_s, rs_s, lnA, w, lq, lm);
                __syncthreads();

                // head pairs: waves 0..5 compute QKV (h2 = wv/3, sec = wv%3)
                for (int pair = 0; pair < 4; ++pair){
                    if (w < 6){
                        int h2 = w / 3, sec = w % 3;
                        int h = pair*2 + h2;
                        floatx4 acc[4][4] = {{z,z,z,z},{z,z,z,z},{z,z,z,z},{z,z,z,z}};
                        const unsigned short* wsec = wqkv + (size_t)(sec*512 + h*64) * DIM;
                        for (int kk = 0; kk < 8; ++kk)
                            mma44(lnA + kk*4608, 72, wsec + kk*64, DIM, acc, lm, lq);
                        const float* bias = ((sec == 0) ? p.bq : (sec == 1) ? p.bk : p.bv)
                                            + l*DIM + h*64;
                        float bb[4];
                        #pragma unroll
                        for (int n = 0; n < 4; ++n) bb[n] = bias[n*16 + lm];
                        unsigned short* dst = QKV_s + (h2*3 + sec)*4608;
                        #pragma unroll
                        for (int m = 0; m < 4; ++m)
                        #pragma unroll
                        for (int i = 0; i < 4; ++i)
                        #pragma unroll
                        for (int n = 0; n < 4; ++n)
                            dst[(m*16 + lq*4 + i)*72 + n*16 + lm] = f2b(acc[m][n][i] + bb[n]);
                    }
                    __syncthreads();

                    // scores + 2-token softmax
                    if (threadIdx.x < 128){
                        int h2s = threadIdx.x >> 6, row = threadIdx.x & 63, pp = row & 31;
                        const unsigned short* Qr = QKV_s + (h2s*3 + 0)*4608 + row*72;
                        const unsigned short* K0 = QKV_s + (h2s*3 + 1)*4608 + pp*72;
                        const unsigned short* K1 = K0 + 32*72;
                        float s0 = 0.f, s1 = 0.f;
                        #pragma unroll
                        for (int d8 = 0; d8 < 8; ++d8){
                            short8 qa = *(const short8*)(Qr + d8*8);
                            short8 ka = *(const short8*)(K0 + d8*8);
                            short8 kb = *(const short8*)(K1 + d8*8);
                            #pragma unroll
                            for (int j = 0; j < 8; ++j){
                                float q = b2f((unsigned short)qa[j]);
                                s0 += q * b2f((unsigned short)ka[j]);
                                s1 += q * b2f((unsigned short)kb[j]);
                            }
                        }
                        s0 *= 0.125f; s1 *= 0.125f;
                        float mx = fmaxf(s0, s1);
                        float e0 = __expf(s0 - mx), e1 = __expf(s1 - mx);
                        float inv = 1.f / (e0 + e1);
                        p_lds[h2s*128 + row*2 + 0] = e0 * inv;
                        p_lds[h2s*128 + row*2 + 1] = e1 * inv;
                    }
                    __syncthreads();

                    // O = P @ V -> overwrite Q region (sec 0) of each h2
                    {
                        int h2s = threadIdx.x >> 8, rr2 = threadIdx.x & 255;
                        int row = rr2 >> 2, dseg = rr2 & 3, pp = row & 31;
                        float p0 = p_lds[h2s*128 + row*2 + 0];
                        float p1 = p_lds[h2s*128 + row*2 + 1];
                        const unsigned short* V = QKV_s + (h2s*3 + 2)*4608;
                        const unsigned short* v0 = V + pp*72 + dseg*16;
                        const unsigned short* v1 = V + (32 + pp)*72 + dseg*16;
                        unsigned short o[16];
                        #pragma unroll
                        for (int j = 0; j < 16; ++j)
                            o[j] = f2b(p0 * b2f(v0[j]) + p1 * b2f(v1[j]));
                        int4* dst = (int4*)(QKV_s + h2s*3*4608 + row*72 + dseg*16);
                        dst[0] = *(int4*)o;
                        dst[1] = *(int4*)(o + 8);
                    }
                    __syncthreads();

                    // O-proj: accumulate straight into residual registers
                    mma44(QKV_s + 0,      72, wol + (size_t)(w*64)*DIM + pair*128 +  0, DIM, sr, lm, lq);
                    mma44(QKV_s + 3*4608, 72, wol + (size_t)(w*64)*DIM + pair*128 + 64, DIM, sr, lm, lq);
                    __syncthreads();
                }
                // + bo (once)
                {
                    float bb[4];
                    #pragma unroll
                    for (int n = 0; n < 4; ++n) bb[n] = p.bo[l*DIM + w*64 + n*16 + lm];
                    #pragma unroll
                    for (int m = 0; m < 4; ++m)
                    #pragma unroll
                    for (int n = 0; n < 4; ++n)
                    #pragma unroll
                    for (int i = 0; i < 4; ++i)
                        sr[m][n][i] += bb[n];
                }

                // ---- P2: LN2 -> lnA (once), 8 slices of 256 h1-cols ----
                ln_stats_reg(sr, red, mu_s, rs_s, w, lq, lm);
                stage_lnA_reg(sr, p.ln2s + l*DIM, p.ln2b + l*DIM, mu_s, rs_s, lnA, w, lq, lm);
                __syncthreads();

                for (int sl = 0; sl < 8; ++sl){
                    floatx4 a1[4][2] = {{z,z},{z,z},{z,z},{z,z}};
                    const unsigned short* w1b = w1l + (size_t)(sl*256 + w*32) * DIM;
                    for (int kk = 0; kk < 8; ++kk)
                        mma42(lnA + kk*4608, 72, w1b + kk*64, DIM, a1, lm, lq);
                    // bias + gelu -> h1_s
                    {
                        const float* b1l = p.b1 + l*MLPD + sl*256 + w*32;
                        float bb[2];
                        #pragma unroll
                        for (int n = 0; n < 2; ++n) bb[n] = b1l[n*16 + lm];
                        #pragma unroll
                        for (int m = 0; m < 4; ++m)
                        #pragma unroll
                        for (int n = 0; n < 2; ++n)
                        #pragma unroll
                        for (int i = 0; i < 4; ++i){
                            float v = a1[m][n][i] + bb[n];
                            float u = 0.7978845608028654f * (v + 0.044715f * v * v * v);
                            float e = __expf(2.f * u);
                            float th = 1.f - 2.f / (1.f + e);
                            h1_s[(m*16 + lq*4 + i)*264 + w*32 + n*16 + lm] = f2b(0.5f * v * (1.f + th));
                        }
                    }
                    __syncthreads();
                    // MLP2 partial (K=256): accumulate into residual registers
                    #pragma unroll
                    for (int c = 0; c < 4; ++c)
                        mma44(h1_s + c*64, 264,
                              w2l + (size_t)(w*64)*MLPD + sl*256 + c*64, MLPD, sr, lm, lq);
                    __syncthreads();
                }
                // + b2 (once)
                {
                    float bb[4];
                    #pragma unroll
                    for (int n = 0; n < 4; ++n) bb[n] = p.b2[l*DIM + w*64 + n*16 + lm];
                    #pragma unroll
                    for (int m = 0; m < 4; ++m)
                    #pragma unroll
                    for (int n = 0; n < 4; ++n)
                    #pragma unroll
                    for (int i = 0; i < 4; ++i)
                        sr[m][n][i] += bb[n];
                }
            }

            // ======== write out[t,b] = obs-token rows (sr[2..3]) ========
            #pragma unroll
            for (int m2 = 0; m2 < 2; ++m2)
            #pragma unroll
            for (int i = 0; i < 4; ++i){
                int pp = m2*16 + lq*4 + i;
                unsigned pi = pinfo[pp];
                if (pi != INVALID_PAIR){
                    float* o = p.out + (size_t)pi * DIM + w*64;
                    #pragma unroll
                    for (int n = 0; n < 4; ++n)
                        o[n*16 + lm] = sr[2 + m2][n][i];
                }
            }
        }
        ++gen; gbar(p.bar, gen);
    }
}

// ---------------- fallback per-phase kernels (used only if cooperative launch fails) ----------------
static __device__ __forceinline__ void stage64(const unsigned short* __restrict__ g,
        int rstride, unsigned short* lds){
    int r = threadIdx.x >> 2, s = threadIdx.x & 3;
    const int4* src = (const int4*)(g + (size_t)r * rstride + s * 16);
    int4* dst = (int4*)(lds + r * 72 + s * 16);
    dst[0] = src[0];
    dst[1] = src[1];
}

static __device__ __forceinline__ void mma_chunk(const unsigned short* __restrict__ A_s, int astride,
        const unsigned short* __restrict__ B_s, floatx4 acc[2][2], int wm, int wn, int lm, int lq){
    #pragma unroll
    for (int ks = 0; ks < 2; ++ks){
        short8 a0 = *(const short8*)(A_s + (wm*32 + lm) * astride + ks*32 + lq*8);
        short8 a1 = *(const short8*)(A_s + (wm*32 + 16 + lm) * astride + ks*32 + lq*8);
        short8 b0 = *(const short8*)(B_s + (wn*32 + lm) * 72 + ks*32 + lq*8);
        short8 b1 = *(const short8*)(B_s + (wn*32 + 16 + lm) * 72 + ks*32 + lq*8);
        acc[0][0] = __builtin_amdgcn_mfma_f32_16x16x32_bf16(a0, b0, acc[0][0], 0, 0, 0);
        acc[0][1] = __builtin_amdgcn_mfma_f32_16x16x32_bf16(a0, b1, acc[0][1], 0, 0, 0);
        acc[1][0] = __builtin_amdgcn_mfma_f32_16x16x32_bf16(a1, b0, acc[1][0], 0, 0, 0);
        acc[1][1] = __builtin_amdgcn_mfma_f32_16x16x32_bf16(a1, b1, acc[1][1], 0, 0, 0);
    }
}

static __device__ __forceinline__ void ln_stats(const float* __restrict__ seq, int row0,
        float* mu_s, float* rs_s, float* red){
    int r = threadIdx.x >> 2, p = threadIdx.x & 3;
    const float* s = seq + (size_t)(row0 + r) * DIM + p * 128;
    float sm = 0.f, ss = 0.f;
    for (int k = 0; k < 128; k += 4){
        float4 v = *(const float4*)(s + k);
        sm += v.x + v.y + v.z + v.w;
        ss += v.x*v.x + v.y*v.y + v.z*v.z + v.w*v.w;
    }
    red[r*8 + p] = sm;
    red[r*8 + 4 + p] = ss;
    __syncthreads();
    if (threadIdx.x < 64){
        int rr = threadIdx.x;
        float s4 = red[rr*8+0] + red[rr*8+1] + red[rr*8+2] + red[rr*8+3];
        float q4 = red[rr*8+4] + red[rr*8+5] + red[rr*8+6] + red[rr*8+7];
        float mu = s4 * (1.f / DIM);
        float var = q4 * (1.f / DIM) - mu * mu;
        mu_s[rr] = mu;
        rs_s[rr] = rsqrtf(var + 1e-6f);
    }
    __syncthreads();
}

static __device__ __forceinline__ void stageA_ln(const float* __restrict__ seq, int row0, int kk,
        const float* __restrict__ lns, const float* __restrict__ lnb,
        const float* mu_s, const float* rs_s, unsigned short* lds){
    int r = threadIdx.x >> 2, s = threadIdx.x & 3;
    const float* src = seq + (size_t)(row0 + r) * DIM + kk + s * 16;
    float mu = mu_s[r], rs = rs_s[r];
    unsigned short tmp[16];
    #pragma unroll
    for (int j = 0; j < 16; ++j){
        float g = lns[kk + s*16 + j];
        float bb = lnb[kk + s*16 + j];
        tmp[j] = f2b((src[j] - mu) * rs * g + bb);
    }
    int4* dst = (int4*)(lds + r * 72 + s * 16);
    dst[0] = *(int4*)(tmp);
    dst[1] = *(int4*)(tmp + 8);
}

__global__ __launch_bounds__(256) void k_memgemm(int t,
        const float* __restrict__ obs, const int* __restrict__ dones,
        const float* __restrict__ mem0, const float* __restrict__ seqprev,
        const unsigned short* __restrict__ wT, float* __restrict__ seqcur,
        float* __restrict__ outprev){
    __shared__ unsigned short A_s[64*72];
    __shared__ unsigned short B_s[64*72];
    int n0 = blockIdx.x * 64, m0 = blockIdx.y * 64;
    int wave = threadIdx.x >> 6, lane = threadIdx.x & 63;
    int wm = wave >> 1, wn = wave & 1, lm = lane & 15, lq = lane >> 4;
    floatx4 z = {0.f, 0.f, 0.f, 0.f};
    floatx4 acc[2][2] = {{z, z}, {z, z}};
    for (int kk = 0; kk < DIM; kk += 64){
        __syncthreads();
        {
            int r = threadIdx.x >> 2, s = threadIdx.x & 3;
            int b = m0 + r;
            int done = dones[b];
            unsigned short tmp[16];
            if (t == 0){
                const float* src = mem0 + (size_t)b * DIM + kk + s * 16;
                #pragma unroll
                for (int j = 0; j < 16; ++j) tmp[j] = done ? (unsigned short)0 : f2b(src[j]);
            } else {
                const float* src = seqprev + (size_t)(2*b + 1) * DIM + kk + s * 16;
                #pragma unroll
                for (int j = 0; j < 16; ++j){
                    float x = src[j];
                    if (blockIdx.x == 0) outprev[(size_t)b * DIM + kk + s*16 + j] = x;
                    tmp[j] = done ? (unsigned short)0 : f2b(x);
                }
            }
            int4* dst = (int4*)(A_s + r * 72 + s * 16);
            dst[0] = *(int4*)tmp;
            dst[1] = *(int4*)(tmp + 8);
        }
        stage64(wT + (size_t)n0 * DIM + kk, DIM, B_s);
        __syncthreads();
        mma_chunk(A_s, 72, B_s, acc, wm, wn, lm, lq);
    }
    #pragma unroll
    for (int fm = 0; fm < 2; ++fm)
    #pragma unroll
    for (int fn = 0; fn < 2; ++fn)
    #pragma unroll
    for (int i = 0; i < 4; ++i){
        int b = m0 + wm*32 + fm*16 + lq*4 + i;
        int c = n0 + wn*32 + fn*16 + lm;
        seqcur[(size_t)(2*b) * DIM + c] = acc[fm][fn][i];
        seqcur[(size_t)(2*b + 1) * DIM + c] = obs[(size_t)b * DIM + c];
    }
}

__global__ __launch_bounds__(256) void k_qkv(const float* __restrict__ seq,
        const unsigned short* __restrict__ wT,
        const float* __restrict__ bq, const float* __restrict__ bk,
        const float* __restrict__ bv,
        const float* __restrict__ lns, const float* __restrict__ lnb,
        unsigned short* __restrict__ qkv){
    __shared__ unsigned short A_s[64*72];
    __shared__ unsigned short B_s[64*72];
    __shared__ float red[64*8];
    __shared__ float mu_s[64], rs_s[64];
    int n0 = blockIdx.x * 64, m0 = blockIdx.y * 64;
    ln_stats(seq, m0, mu_s, rs_s, red);
    int wave = threadIdx.x >> 6, lane = threadIdx.x & 63;
    int wm = wave >> 1, wn = wave & 1, lm = lane & 15, lq = lane >> 4;
    floatx4 z = {0.f, 0.f, 0.f, 0.f};
    floatx4 acc[2][2] = {{z, z}, {z, z}};
    for (int kk = 0; kk < DIM; kk += 64){
        __syncthreads();
        stageA_ln(seq, m0, kk, lns, lnb, mu_s, rs_s, A_s);
        stage64(wT + (size_t)n0 * DIM + kk, DIM, B_s);
        __syncthreads();
        mma_chunk(A_s, 72, B_s, acc, wm, wn, lm, lq);
    }
    int sec = n0 >> 9;
    const float* bias = (sec == 0) ? bq : ((sec == 1) ? bk : bv);
    int nsec = n0 & 511;
    #pragma unroll
    for (int fm = 0; fm < 2; ++fm)
    #pragma unroll
    for (int fn = 0; fn < 2; ++fn)
    #pragma unroll
    for (int i = 0; i < 4; ++i){
        int row = m0 + wm*32 + fm*16 + lq*4 + i;
        int cl = wn*32 + fn*16 + lm;
        float v = acc[fm][fn][i] + bias[nsec + cl];
        qkv[(size_t)row * QKVW + n0 + cl] = f2b(v);
    }
}

__global__ __launch_bounds__(256) void k_attno(const unsigned short* __restrict__ qkv,
        const unsigned short* __restrict__ wT,
        const float* __restrict__ bo, float* __restrict__ seq){
    __shared__ unsigned short O_s[64*264];
    __shared__ unsigned short B_s[64*72];
    int n0 = blockIdx.x * 64, m0 = blockIdx.y * 64;
    int sp = blockIdx.z;
    if (threadIdx.x < 128){
        int b_l = threadIdx.x >> 2, h_l = threadIdx.x & 3;
        int h = sp * 4 + h_l;
        const unsigned short* q0 = qkv + (size_t)(m0 + 2*b_l) * QKVW + h * 64;
        const unsigned short* q1 = q0 + QKVW;
        const unsigned short* k0p = q0 + 512;
        const unsigned short* k1p = k0p + QKVW;
        const unsigned short* v0p = q0 + 1024;
        const unsigned short* v1p = v0p + QKVW;
        float s00 = 0, s01 = 0, s10 = 0, s11 = 0;
        for (int f8 = 0; f8 < 8; ++f8){
            short8 a0 = *(const short8*)(q0 + f8*8);
            short8 a1 = *(const short8*)(q1 + f8*8);
            short8 c0 = *(const short8*)(k0p + f8*8);
            short8 c1 = *(const short8*)(k1p + f8*8);
            #pragma unroll
            for (int j = 0; j < 8; ++j){
                float qa = b2f((unsigned short)a0[j]);
                float qb = b2f((unsigned short)a1[j]);
                float ka = b2f((unsigned short)c0[j]);
                float kb = b2f((unsigned short)c1[j]);
                s00 += qa*ka; s01 += qa*kb; s10 += qb*ka; s11 += qb*kb;
            }
        }
        s00 *= 0.125f; s01 *= 0.125f; s10 *= 0.125f; s11 *= 0.125f;
        float m0v = fmaxf(s00, s01), m1v = fmaxf(s10, s11);
        float e00 = __expf(s00 - m0v), e01 = __expf(s01 - m0v);
        float e10 = __expf(s10 - m1v), e11 = __expf(s11 - m1v);
        float i0 = 1.f / (e00 + e01), i1 = 1.f / (e10 + e11);
        float p00 = e00*i0, p01 = e01*i0, p10 = e10*i1, p11 = e11*i1;
        for (int f8 = 0; f8 < 8; ++f8){
            short8 va = *(const short8*)(v0p + f8*8);
            short8 vb = *(const short8*)(v1p + f8*8);
            unsigned short o0[8], o1[8];
            #pragma unroll
            for (int j = 0; j < 8; ++j){
                float x0 = b2f((unsigned short)va[j]);
                float x1 = b2f((unsigned short)vb[j]);
                o0[j] = f2b(p00*x0 + p01*x1);
                o1[j] = f2b(p10*x0 + p11*x1);
            }
            *(int4*)(O_s + (2*b_l) * 264 + h_l*64 + f8*8) = *(int4*)o0;
            *(int4*)(O_s + (2*b_l + 1) * 264 + h_l*64 + f8*8) = *(int4*)o1;
        }
    }
    int wave = threadIdx.x >> 6, lane = threadIdx.x & 63;
    int wm = wave >> 1, wn = wave & 1, lm = lane & 15, lq = lane >> 4;
    floatx4 z = {0.f, 0.f, 0.f, 0.f};
    floatx4 acc[2][2] = {{z, z}, {z, z}};
    for (int c = 0; c < 4; ++c){
        int kkg = sp * 256 + c * 64;
        __syncthreads();
        stage64(wT + (size_t)n0 * DIM + kkg, DIM, B_s);
        __syncthreads();
        mma_chunk(O_s + c * 64, 264, B_s, acc, wm, wn, lm, lq);
    }
    #pragma unroll
    for (int fm = 0; fm < 2; ++fm)
    #pragma unroll
    for (int fn = 0; fn < 2; ++fn)
    #pragma unroll
    for (int i = 0; i < 4; ++i){
        int row = m0 + wm*32 + fm*16 + lq*4 + i;
        int cc = n0 + wn*32 + fn*16 + lm;
        float v = acc[fm][fn][i];
        if (sp == 0) v += bo[cc];
        atomicAdd(&seq[(size_t)row * DIM + cc], v);
    }
}

__global__ __launch_bounds__(256) void k_mlp1(const float* __restrict__ seq,
        const unsigned short* __restrict__ wT, const float* __restrict__ b1,
        const float* __restrict__ lns, const float* __restrict__ lnb,
        unsigned short* __restrict__ h1){
    __shared__ unsigned short A_s[64*72];
    __shared__ unsigned short B_s[64*72];
    __shared__ float red[64*8];
    __shared__ float mu_s[64], rs_s[64];
    int n0 = blockIdx.x * 64, m0 = blockIdx.y * 64;
    ln_stats(seq, m0, mu_s, rs_s, red);
    int wave = threadIdx.x >> 6, lane = threadIdx.x & 63;
    int wm = wave >> 1, wn = wave & 1, lm = lane & 15, lq = lane >> 4;
    floatx4 z = {0.f, 0.f, 0.f, 0.f};
    floatx4 acc[2][2] = {{z, z}, {z, z}};
    for (int kk = 0; kk < DIM; kk += 64){
        __syncthreads();
        stageA_ln(seq, m0, kk, lns, lnb, mu_s, rs_s, A_s);
        stage64(wT + (size_t)n0 * DIM + kk, DIM, B_s);
        __syncthreads();
        mma_chunk(A_s, 72, B_s, acc, wm, wn, lm, lq);
    }
    #pragma unroll
    for (int fm = 0; fm < 2; ++fm)
    #pragma unroll
    for (int fn = 0; fn < 2; ++fn)
    #pragma unroll
    for (int i = 0; i < 4; ++i){
        int row = m0 + wm*32 + fm*16 + lq*4 + i;
        int cc = n0 + wn*32 + fn*16 + lm;
        float v = acc[fm][fn][i] + b1[cc];
        float g = 0.5f * v * (1.f + tanhf(0.7978845608028654f * (v + 0.044715f * v * v * v)));
        h1[(size_t)row * MLPD + cc] = f2b(g);
    }
}

__global__ __launch_bounds__(256) void k_mlp2(const unsigned short* __restrict__ h1,
        const unsigned short* __restrict__ wT, const float* __restrict__ b2,
        float* __restrict__ seq){
    __shared__ unsigned short A_s[64*72];
    __shared__ unsigned short B_s[64*72];
    int n0 = blockIdx.x * 64, m0 = blockIdx.y * 64;
    int sp = blockIdx.z;
    int wave = threadIdx.x >> 6, lane = threadIdx.x & 63;
    int wm = wave >> 1, wn = wave & 1, lm = lane & 15, lq = lane >> 4;
    floatx4 z = {0.f, 0.f, 0.f, 0.f};
    floatx4 acc[2][2] = {{z, z}, {z, z}};
    for (int c = 0; c < 8; ++c){
        int kk = sp * 512 + c * 64;
        __syncthreads();
        stage64(h1 + (size_t)m0 * MLPD + kk, MLPD, A_s);
        stage64(wT + (size_t)n0 * MLPD + kk, MLPD, B_s);
        __syncthreads();
        mma_chunk(A_s, 72, B_s, acc, wm, wn, lm, lq);
    }
    #pragma unroll
    for (int fm = 0; fm < 2; ++fm)
    #pragma unroll
    for (int fn = 0; fn < 2; ++fn)
    #pragma unroll
    for (int i = 0; i < 4; ++i){
        int row = m0 + wm*32 + fm*16 + lq*4 + i;
        int cc = n0 + wn*32 + fn*16 + lm;
        float v = acc[fm][fn][i];
        if (sp == 0) v += b2[cc];
        atomicAdd(&seq[(size_t)row * DIM + cc], v);
    }
}

__global__ __launch_bounds__(256) void k_flush(const float* __restrict__ seq,
        float* __restrict__ out){
    int idx = blockIdx.x * 256 + threadIdx.x;
    int b = idx >> 9, c = idx & 511;
    out[idx] = seq[(size_t)(2*b + 1) * DIM + c];
}

// ---------------- host launch ----------------
extern "C" void kernel_launch(void* const* d_in, const int* in_sizes, int n_in,
                              void* d_out, int out_size, void* d_ws, size_t ws_size,
                              hipStream_t stream){
    const float* obs  = (const float*)d_in[0];
    const int*   dones= (const int*)d_in[1];
    const float* mem0 = (const float*)d_in[2];
    const float* memk = (const float*)d_in[3];
    const float* ln1s = (const float*)d_in[4];
    const float* ln1b = (const float*)d_in[5];
    const float* wq   = (const float*)d_in[6];
    const float* bq   = (const float*)d_in[7];
    const float* wk   = (const float*)d_in[8];
    const float* bk   = (const float*)d_in[9];
    const float* wv   = (const float*)d_in[10];
    const float* bv   = (const float*)d_in[11];
    const float* wo   = (const float*)d_in[12];
    const float* bo   = (const float*)d_in[13];
    const float* ln2s = (const float*)d_in[14];
    const float* ln2b = (const float*)d_in[15];
    const float* w1   = (const float*)d_in[16];
    const float* b1   = (const float*)d_in[17];
    const float* w2   = (const float*)d_in[18];
    const float* b2   = (const float*)d_in[19];
    float* out = (float*)d_out;

    char* ws = (char*)d_ws;
    unsigned short* memkT = (unsigned short*)(ws + 0);          // 512*512 bf16
    unsigned short* qkvT  = (unsigned short*)(ws + 524288);     // 4*1536*512
    unsigned short* woT   = (unsigned short*)(ws + 6815744);    // 4*512*512
    unsigned short* w1T   = (unsigned short*)(ws + 8912896);    // 4*2048*512
    unsigned short* w2T   = (unsigned short*)(ws + 17301504);   // 4*512*2048
    // persistent-path arrays (alias the fallback seq0 region; mutually exclusive)
    unsigned* idxg        = (unsigned*)(ws + 25690112);         // 65536 u32
    unsigned* offg        = (unsigned*)(ws + 25952256);         // 258 u32
    unsigned* bar         = (unsigned*)(ws + 25954304);         // 32 u32
    // fallback-path buffers (old layout)
    float* seq0           = (float*)(ws + 25690112);
    float* seq1           = (float*)(ws + 26738688);
    unsigned short* qkv   = (unsigned short*)(ws + 27787264);
    unsigned short* h1    = (unsigned short*)(ws + 29360128);

    dim3 blk(256);
    k_transpose<<<dim3(8, 8), blk, 0, stream>>>(memk, memkT, 512, 512);
    for (int l = 0; l < NLAY; ++l){
        k_transpose<<<dim3(8, 8), blk, 0, stream>>>(wq + (size_t)l*262144, qkvT + (size_t)l*786432,          512, 512);
        k_transpose<<<dim3(8, 8), blk, 0, stream>>>(wk + (size_t)l*262144, qkvT + (size_t)l*786432 + 262144, 512, 512);
        k_transpose<<<dim3(8, 8), blk, 0, stream>>>(wv + (size_t)l*262144, qkvT + (size_t)l*786432 + 524288, 512, 512);
        k_transpose<<<dim3(8, 8), blk, 0, stream>>>(wo + (size_t)l*262144, woT + (size_t)l*262144,           512, 512);
        k_transpose<<<dim3(8, 32), blk, 0, stream>>>(w1 + (size_t)l*1048576, w1T + (size_t)l*1048576,        512, 2048);
        k_transpose<<<dim3(32, 8), blk, 0, stream>>>(w2 + (size_t)l*1048576, w2T + (size_t)l*1048576,        2048, 512);
    }
    k_depth<<<dim3(1), blk, 0, stream>>>(dones, offg, idxg);
    k_zero<<<dim3(1), blk, 0, stream>>>(bar);

    P prm;
    prm.obs = obs; prm.dones = dones; prm.mem0 = mem0;
    prm.memkT = memkT; prm.qkvT = qkvT; prm.woT = woT; prm.w1T = w1T; prm.w2T = w2T;
    prm.ln1s = ln1s; prm.ln1b = ln1b; prm.bq = bq; prm.bk = bk; prm.bv = bv;
    prm.bo = bo; prm.ln2s = ln2s; prm.ln2b = ln2b; prm.b1 = b1; prm.b2 = b2;
    prm.off = offg; prm.idx = idxg; prm.out = out; prm.bar = bar;

    hipError_t ce = hipFuncSetAttribute((const void*)k_persist,
            hipFuncAttributeMaxDynamicSharedMemorySize, 134784);
    if (ce == hipSuccess){
        void* kargs[] = { (void*)&prm };
        ce = hipLaunchCooperativeKernel((const void*)k_persist,
                dim3(GRID), dim3(512), kargs, 134784, stream);
    }

    if (ce != hipSuccess){
        // fallback: per-phase launch sequence (proven path)
        for (int t = 0; t < NT; ++t){
            float* scur  = (t & 1) ? seq1 : seq0;
            float* sprev = (t & 1) ? seq0 : seq1;
            k_memgemm<<<dim3(8, 4), blk, 0, stream>>>(t,
                    obs + (size_t)t * NB * DIM, dones + t * NB, mem0,
                    sprev, memkT, scur,
                    out + (size_t)(t > 0 ? t - 1 : 0) * NB * DIM);
            for (int l = 0; l < NLAY; ++l){
                k_qkv<<<dim3(24, 8), blk, 0, stream>>>(scur, qkvT + (size_t)l*786432,
                        bq + l*512, bk + l*512, bv + l*512, ln1s + l*512, ln1b + l*512, qkv);
                k_attno<<<dim3(8, 8, 2), blk, 0, stream>>>(qkv, woT + (size_t)l*262144, bo + l*512, scur);
                k_mlp1<<<dim3(32, 8, 1), blk, 0, stream>>>(scur, w1T + (size_t)l*1048576, b1 + l*2048,
                        ln2s + l*512, ln2b + l*512, h1);
                k_mlp2<<<dim3(8, 8, 4), blk, 0, stream>>>(h1, w2T + (size_t)l*1048576, b2 + l*512, scur);
            }
        }
        k_flush<<<dim3(512), blk, 0, stream>>>(((NT - 1) & 1) ? seq1 : seq0,
                out + (size_t)(NT - 1) * NB * DIM);
    }
}